// Round 3
// baseline (1523.164 us; speedup 1.0000x reference)
//
#include <hip/hip_runtime.h>
#include <stdint.h>
#include <math.h>

#define TT 516
#define BB 16
#define DD 512
#define LL 512
#define NN 512
#define HH 8
#define DHD 64
#define DFFN 2048
#define PP 336
#define MM 512
#define KNN 10
#define BT (BB*TT)      /* 8256 */
#define PN (PP*NN)      /* 172032 */
#define SKC 32          /* sims k-chunks */
#define SCHUNK (PN/SKC) /* 5376 */
#define SSTG (SCHUNK/256) /* 21 stages */

using f32x4  = __attribute__((ext_vector_type(4))) float;
using bf16x8 = __attribute__((ext_vector_type(8))) __bf16;
using u16x8  = __attribute__((ext_vector_type(8))) unsigned short;

__device__ __forceinline__ float gelu_tanh(float x){
    float x3 = x*x*x;
    return 0.5f*x*(1.0f + tanhf(0.7978845608028654f*(x + 0.044715f*x3)));
}

__device__ __forceinline__ uint16_t f2bf(float x){
    uint32_t u = __builtin_bit_cast(uint32_t, x);
    uint32_t r = (u + 0x7FFFu + ((u >> 16) & 1u)) >> 16;
    return (uint16_t)r;
}

__device__ __forceinline__ void split_bf(float x, uint16_t& hi, uint16_t& lo){
    uint32_t u  = __builtin_bit_cast(uint32_t, x);
    uint32_t hr = (u + 0x7FFFu + ((u >> 16) & 1u)) & 0xFFFF0000u;
    float hf = __builtin_bit_cast(float, hr);
    hi = (uint16_t)(hr >> 16);
    lo = f2bf(x - hf);
}

__device__ __forceinline__ void gl16(const uint16_t* g, uint16_t* l){
    __builtin_amdgcn_global_load_lds(
        (const __attribute__((address_space(1))) unsigned int*)(const void*)g,
        (__attribute__((address_space(3))) unsigned int*)(void*)l, 16, 0, 0);
}

#define EPI_F32   1
#define EPI_BF16  2
#define EPI_GELU  4
#define EPI_PREDT 8
#define EPI_QKV   16

// ---------------------------------------------------------------------------
// Split-bf16 MFMA GEMM (unchanged from round 2)
// ---------------------------------------------------------------------------
template<int BN, int FLAGS>
__global__ __launch_bounds__(256)
void bgemm(const uint16_t* __restrict__ Ah, const uint16_t* __restrict__ Al,
           const uint16_t* __restrict__ Bh, const uint16_t* __restrict__ Bl,
           const float* __restrict__ bias, float* __restrict__ Cf,
           uint16_t* __restrict__ Cbh, uint16_t* __restrict__ Cbl,
           int Msz, int Nsz, int Ksz)
{
    constexpr int FN = BN/32;
    __shared__ uint16_t As0[4096], As1[4096];
    __shared__ uint16_t Bs0[BN*32], Bs1[BN*32];

    const int tid  = threadIdx.x;
    const int lane = tid & 63;
    const int wu   = __builtin_amdgcn_readfirstlane(tid >> 6);
    const int wm   = wu >> 1, wn = wu & 1;
    const int m0   = blockIdx.y * 128;
    const int n0   = blockIdx.x * BN;

    const int r0c = tid >> 2;
    const int cc  = tid & 3;
    const int sw  = (r0c ^ (r0c >> 2)) & 3;
    const int csw = (cc ^ sw) * 8;
    int rA0 = m0 + r0c;      if (rA0 > Msz-1) rA0 = Msz-1;
    int rA1 = m0 + r0c + 64; if (rA1 > Msz-1) rA1 = Msz-1;
    int rB0 = n0 + r0c;      if (rB0 > Nsz-1) rB0 = Nsz-1;
    int rB1 = n0 + r0c + 64; if (rB1 > Nsz-1) rB1 = Nsz-1;
    const uint16_t* pAh0 = Ah + (size_t)rA0*Ksz + csw;
    const uint16_t* pAh1 = Ah + (size_t)rA1*Ksz + csw;
    const uint16_t* pAl0 = Al + (size_t)rA0*Ksz + csw;
    const uint16_t* pAl1 = Al + (size_t)rA1*Ksz + csw;
    const uint16_t* pBh0 = Bh + (size_t)rB0*Ksz + csw;
    const uint16_t* pBh1 = Bh + (size_t)rB1*Ksz + csw;
    const uint16_t* pBl0 = Bl + (size_t)rB0*Ksz + csw;
    const uint16_t* pBl1 = Bl + (size_t)rB1*Ksz + csw;

    f32x4 acc[4][FN];
#pragma unroll
    for (int i=0;i<4;i++)
#pragma unroll
        for (int j=0;j<FN;j++) acc[i][j] = (f32x4){0.f,0.f,0.f,0.f};

    const int lc16  = lane & 15;
    const int slot8 = (((lane>>4) ^ (lane&3) ^ ((lane>>2)&3))) * 8;
    const int rAf   = (wm*64 + lc16) * 32 + slot8;
    const int rBf   = (wn*(BN/2) + lc16) * 32 + slot8;

    for (int kt = 0; kt < Ksz; kt += 32){
        gl16(pAh0 + kt, &As0[wu*512]);
        gl16(pAh1 + kt, &As0[2048 + wu*512]);
        gl16(pAl0 + kt, &As1[wu*512]);
        gl16(pAl1 + kt, &As1[2048 + wu*512]);
        if (BN == 128){
            gl16(pBh0 + kt, &Bs0[wu*512]);
            gl16(pBh1 + kt, &Bs0[2048 + wu*512]);
            gl16(pBl0 + kt, &Bs1[wu*512]);
            gl16(pBl1 + kt, &Bs1[2048 + wu*512]);
        } else {
            gl16(pBh0 + kt, &Bs0[wu*512]);
            gl16(pBl0 + kt, &Bs1[wu*512]);
        }
        __syncthreads();

        bf16x8 ah[4], al[4], bh[FN], bl[FN];
#pragma unroll
        for (int fm=0; fm<4; fm++){
            ah[fm] = __builtin_bit_cast(bf16x8, *(const u16x8*)&As0[rAf + fm*512]);
            al[fm] = __builtin_bit_cast(bf16x8, *(const u16x8*)&As1[rAf + fm*512]);
        }
#pragma unroll
        for (int fn=0; fn<FN; fn++){
            bh[fn] = __builtin_bit_cast(bf16x8, *(const u16x8*)&Bs0[rBf + fn*512]);
            bl[fn] = __builtin_bit_cast(bf16x8, *(const u16x8*)&Bs1[rBf + fn*512]);
        }
#pragma unroll
        for (int fm=0; fm<4; fm++)
#pragma unroll
            for (int fn=0; fn<FN; fn++){
                acc[fm][fn] = __builtin_amdgcn_mfma_f32_16x16x32_bf16(ah[fm], bh[fn], acc[fm][fn], 0,0,0);
                acc[fm][fn] = __builtin_amdgcn_mfma_f32_16x16x32_bf16(ah[fm], bl[fn], acc[fm][fn], 0,0,0);
                acc[fm][fn] = __builtin_amdgcn_mfma_f32_16x16x32_bf16(al[fm], bh[fn], acc[fm][fn], 0,0,0);
            }
        __syncthreads();
    }

    const int lr4 = (lane >> 4) * 4;
#pragma unroll
    for (int fm=0; fm<4; fm++){
        const int rbase = m0 + wm*64 + fm*16 + lr4;
#pragma unroll
        for (int fn=0; fn<FN; fn++){
            const int col = n0 + wn*(BN/2) + fn*16 + lc16;
            f32x4 v = acc[fm][fn];
            if (FLAGS & EPI_PREDT){
#pragma unroll
                for (int r=0;r<4;r++){
                    int row = rbase + r;
                    if (row < Msz && col < PP){
                        int b = row / TT, t = row - b*TT;
                        if (t < NN)
                            Cf[((size_t)b*PP + col)*NN + t] = v[r] + bias[col];
                    }
                }
            } else {
                const float bcol = bias[col];
#pragma unroll
                for (int r=0;r<4;r++){
                    int row = rbase + r;
                    if (row < Msz){
                        float x = v[r] + bcol;
                        if (FLAGS & EPI_GELU) x = gelu_tanh(x);
                        if (FLAGS & EPI_QKV){
                            Cf[(size_t)(col>>9)*((size_t)BT*512) + (size_t)row*512 + (col&511)] = x;
                        } else {
                            if (FLAGS & EPI_F32) Cf[(size_t)row*Nsz + col] = x;
                        }
                        if (FLAGS & EPI_BF16){
                            uint16_t hi, lo; split_bf(x, hi, lo);
                            Cbh[(size_t)row*Nsz + col] = hi;
                            Cbl[(size_t)row*Nsz + col] = lo;
                        }
                    }
                }
            }
        }
    }
}

// ---------------------------------------------------------------------------
// tok transpose + split (unchanged)
// ---------------------------------------------------------------------------
__global__ __launch_bounds__(256)
void tok_k(const float* __restrict__ xe, const float* __restrict__ xm,
           uint16_t* __restrict__ th, uint16_t* __restrict__ tl)
{
    const int b = blockIdx.z;
    const int t0 = blockIdx.x*32, l0 = blockIdx.y*32;
    __shared__ float tile[32][33];
    const int i = threadIdx.x >> 3;
    const int j4 = (threadIdx.x & 7) * 4;
#pragma unroll
    for (int c=0;c<4;c++){
        int t = t0 + j4 + c;
        float v = 0.0f;
        if (t < 512)      v = xe[((size_t)b*LL + l0+i)*NN + t];
        else if (t < 516) v = xm[((size_t)b*LL + l0+i)*4 + (t-512)];
        tile[i][j4+c] = v;
    }
    __syncthreads();
    int t = t0 + i;
    if (t < TT){
#pragma unroll
        for (int c=0;c<4;c++){
            uint16_t hi, lo; split_bf(tile[j4+c][i], hi, lo);
            size_t idx = ((size_t)b*TT + t)*512 + l0 + j4 + c;
            th[idx] = hi; tl[idx] = lo;
        }
    }
}

// ---------------------------------------------------------------------------
// weight transpose-split (unchanged)
// ---------------------------------------------------------------------------
__global__ __launch_bounds__(256)
void wtr_k(const float* __restrict__ src, uint16_t* __restrict__ dh,
           uint16_t* __restrict__ dl, int Ksz, int Nsz, size_t zstride)
{
    const int z = blockIdx.z;
    src += (size_t)z*Ksz*Nsz; dh += (size_t)z*zstride; dl += (size_t)z*zstride;
    __shared__ float tile[32][33];
    const int kt = blockIdx.y*32, nt = blockIdx.x*32;
    const int i = threadIdx.x >> 3;
    const int j4 = (threadIdx.x & 7) * 4;
#pragma unroll
    for (int c=0;c<4;c++){
        int n = nt + j4 + c;
        tile[i][j4+c] = (n < Nsz) ? src[(size_t)(kt+i)*Nsz + n] : 0.0f;
    }
    __syncthreads();
    int n = nt + i;
    if (n < Nsz){
#pragma unroll
        for (int c=0;c<4;c++){
            uint16_t hi, lo; split_bf(tile[j4+c][i], hi, lo);
            size_t idx = (size_t)n*Ksz + kt + j4 + c;
            dh[idx] = hi; dl[idx] = lo;
        }
    }
}

__global__ void catb_k(const float* __restrict__ bq, const float* __restrict__ bk,
                       const float* __restrict__ bv, float* __restrict__ dst){
    int j = blockIdx.x*256 + threadIdx.x;
    if (j >= 3072) return;
    int layer = j / 1536, r = j - layer*1536;
    float v;
    if (r < 512)       v = bq[layer*512 + r];
    else if (r < 1024) v = bk[layer*512 + r - 512];
    else               v = bv[layer*512 + r - 1024];
    dst[j] = v;
}

// ---------------------------------------------------------------------------
// Flash-style fp32 attention (unchanged)
// ---------------------------------------------------------------------------
__global__ __launch_bounds__(256)
void attn_k(const float* __restrict__ q, const float* __restrict__ k,
            const float* __restrict__ v, uint16_t* __restrict__ oh,
            uint16_t* __restrict__ ol)
{
    const int tt = blockIdx.x;
    const int h  = blockIdx.y;
    const int b  = blockIdx.z;
    const int t0 = tt * 64;
    const int tid = threadIdx.x;
    const int ty = tid >> 4, tx = tid & 15;
    const int ty4 = ty*4, tx4 = tx*4;

    __shared__ float QT[64][68];
    __shared__ float KT[64][68];
    __shared__ float Vs[64][68];
    __shared__ float PT[64][68];

    {
        int r  = tid >> 2;
        int dc = (tid & 3) * 16;
        int t  = t0 + r;
#pragma unroll
        for (int c=0;c<4;c++){
            float4 val;
            if (t < TT) val = *(const float4*)(q + ((size_t)(b*TT + t))*DD + h*DHD + dc + 4*c);
            else { val.x=val.y=val.z=val.w=0.0f; }
            QT[dc+4*c+0][r] = val.x; QT[dc+4*c+1][r] = val.y;
            QT[dc+4*c+2][r] = val.z; QT[dc+4*c+3][r] = val.w;
        }
    }

    float accO[4][4];
    float mrow[4], lrow[4];
#pragma unroll
    for (int i=0;i<4;i++){
        mrow[i] = -1e30f; lrow[i] = 0.0f;
#pragma unroll
        for (int j=0;j<4;j++) accO[i][j] = 0.0f;
    }
    const float scale = 0.125f;

    for (int st=0; st<9; st++){
        int s0 = st*64;
        __syncthreads();
        {
            int r  = tid >> 2;
            int dc = (tid & 3) * 16;
            int s  = s0 + r;
#pragma unroll
            for (int c=0;c<4;c++){
                float4 kv, vv;
                if (s < TT){
                    kv = *(const float4*)(k + ((size_t)(b*TT + s))*DD + h*DHD + dc + 4*c);
                    vv = *(const float4*)(v + ((size_t)(b*TT + s))*DD + h*DHD + dc + 4*c);
                } else { kv.x=kv.y=kv.z=kv.w=0.0f; vv.x=vv.y=vv.z=vv.w=0.0f; }
                KT[dc+4*c+0][r] = kv.x; KT[dc+4*c+1][r] = kv.y;
                KT[dc+4*c+2][r] = kv.z; KT[dc+4*c+3][r] = kv.w;
                *(float4*)&Vs[r][dc+4*c] = vv;
            }
        }
        __syncthreads();
        float sacc[4][4];
#pragma unroll
        for (int i=0;i<4;i++)
#pragma unroll
            for (int j=0;j<4;j++) sacc[i][j] = 0.0f;
#pragma unroll 8
        for (int d=0; d<64; d++){
            float4 av = *(const float4*)&QT[d][ty4];
            float4 bv = *(const float4*)&KT[d][tx4];
            float a[4] = {av.x, av.y, av.z, av.w};
            float bb2[4] = {bv.x, bv.y, bv.z, bv.w};
#pragma unroll
            for (int i=0;i<4;i++)
#pragma unroll
                for (int j=0;j<4;j++)
                    sacc[i][j] = fmaf(a[i], bb2[j], sacc[i][j]);
        }
        float p[4][4];
#pragma unroll
        for (int i=0;i<4;i++){
            float mx = -1e30f;
#pragma unroll
            for (int j=0;j<4;j++){
                float sv = sacc[i][j]*scale;
                if (s0 + tx4 + j >= TT) sv = -1e30f;
                p[i][j] = sv;
                mx = fmaxf(mx, sv);
            }
#pragma unroll
            for (int msk=1; msk<16; msk<<=1) mx = fmaxf(mx, __shfl_xor(mx, msk));
            float mnew  = fmaxf(mrow[i], mx);
            float alpha = __expf(mrow[i] - mnew);
            mrow[i] = mnew;
            float rs = 0.0f;
#pragma unroll
            for (int j=0;j<4;j++){
                float e = __expf(p[i][j] - mnew);
                p[i][j] = e;
                rs += e;
            }
#pragma unroll
            for (int msk=1; msk<16; msk<<=1) rs += __shfl_xor(rs, msk);
            lrow[i] = lrow[i]*alpha + rs;
#pragma unroll
            for (int j=0;j<4;j++) accO[i][j] *= alpha;
        }
#pragma unroll
        for (int j=0;j<4;j++)
#pragma unroll
            for (int i=0;i<4;i++)
                PT[tx4+j][ty4+i] = p[i][j];
        __syncthreads();
#pragma unroll 8
        for (int s=0; s<64; s++){
            float4 pa = *(const float4*)&PT[s][ty4];
            float4 vb = *(const float4*)&Vs[s][tx4];
            float a[4] = {pa.x, pa.y, pa.z, pa.w};
            float bb2[4] = {vb.x, vb.y, vb.z, vb.w};
#pragma unroll
            for (int i=0;i<4;i++)
#pragma unroll
                for (int j=0;j<4;j++)
                    accO[i][j] = fmaf(a[i], bb2[j], accO[i][j]);
        }
    }
#pragma unroll
    for (int i=0;i<4;i++){
        int t = t0 + ty4 + i;
        if (t < TT){
            float inv = 1.0f/lrow[i];
            size_t base = ((size_t)(b*TT + t))*DD + h*DHD + tx4;
#pragma unroll
            for (int j=0;j<4;j++){
                uint16_t hi, lo; split_bf(accO[i][j]*inv, hi, lo);
                oh[base + j] = hi; ol[base + j] = lo;
            }
        }
    }
}

// ---------------------------------------------------------------------------
// Residual + LayerNorm (unchanged)
// ---------------------------------------------------------------------------
__global__ __launch_bounds__(256)
void ln_k(const float* __restrict__ src, const float* __restrict__ res,
          const float* __restrict__ w, const float* __restrict__ bia,
          float* __restrict__ dst, uint16_t* __restrict__ dbh,
          uint16_t* __restrict__ dbl)
{
    const int r = blockIdx.x;
    const int tid = threadIdx.x;
    const float* sp = src + (size_t)r*DD;
    float x0 = sp[tid], x1 = sp[tid + 256];
    if (res){
        x0 += res[(size_t)r*DD + tid];
        x1 += res[(size_t)r*DD + tid + 256];
    }
    float s  = x0 + x1;
    float sq = x0*x0 + x1*x1;
#pragma unroll
    for (int msk=1; msk<64; msk<<=1){
        s  += __shfl_xor(s,  msk);
        sq += __shfl_xor(sq, msk);
    }
    __shared__ float sm[8];
    int wv = tid >> 6, ln = tid & 63;
    if (ln == 0){ sm[wv] = s; sm[wv+4] = sq; }
    __syncthreads();
    s  = sm[0]+sm[1]+sm[2]+sm[3];
    sq = sm[4]+sm[5]+sm[6]+sm[7];
    float mu  = s * (1.0f/512.0f);
    float var = sq * (1.0f/512.0f) - mu*mu;
    float rsd = rsqrtf(var + 1e-5f);
    float y0 = (x0 - mu)*rsd*w[tid]       + bia[tid];
    float y1 = (x1 - mu)*rsd*w[tid + 256] + bia[tid + 256];
    dst[(size_t)r*DD + tid]       = y0;
    dst[(size_t)r*DD + tid + 256] = y1;
    uint16_t hi, lo;
    split_bf(y0, hi, lo); dbh[(size_t)r*DD + tid] = hi;       dbl[(size_t)r*DD + tid] = lo;
    split_bf(y1, hi, lo); dbh[(size_t)r*DD + tid + 256] = hi; dbl[(size_t)r*DD + tid + 256] = lo;
}

// ---------------------------------------------------------------------------
// NEW sims kernel: registers for pred slice, broadcast LDS for bank rows.
// Block = (j-tile of 16 bank rows) x (k-chunk of 5376). 21 stages of 256 elems.
// Thread (w,rep,qq): owns query qq, elem slice (w*4+rep)*16..+16 of each stage.
// ---------------------------------------------------------------------------
__global__ __launch_bounds__(256)
void sims_k(const float* __restrict__ pred, const float* __restrict__ bank,
            float* __restrict__ dotp, float* __restrict__ nrmp)
{
    const int jt = blockIdx.x, kt = blockIdx.y;
    const int tid  = threadIdx.x;
    const int lane = tid & 63;
    const int w    = tid >> 6;
    const int qq   = lane & 15;
    const int rep  = lane >> 4;           // 0..3
    const int sb   = (w*4 + rep)*16;      // elem slice base within stage
    const int srow = tid >> 4;            // staging row 0..15
    const int tau  = tid & 15;

    __shared__ float S[2*16*260];
    float* BS = S;              // [16][260] bank tile
    float* PS = S + 16*260;     // [16][260] pred tile

    const int jr = jt*16 + srow;
    const float* bsrc = (jr < MM) ? (bank + (size_t)jr*PN)
                                  : (pred + (size_t)(jr - MM)*PN);
    bsrc += (size_t)kt*SCHUNK + tau*4;
    const float* psrc = pred + (size_t)srow*PN + (size_t)kt*SCHUNK + tau*4;

    float acc[16];
#pragma unroll
    for (int j=0;j<16;j++) acc[j] = 0.0f;
    float nr = 0.0f;

    for (int st=0; st<SSTG; ++st){
        float4 blv[4], plv[4];
#pragma unroll
        for (int c=0;c<4;c++){
            blv[c] = *(const float4*)(bsrc + c*64);
            plv[c] = *(const float4*)(psrc + c*64);
        }
        __syncthreads();   // previous stage's compute done before overwrite
#pragma unroll
        for (int c=0;c<4;c++){
            *(float4*)&BS[srow*260 + tau*4 + c*64] = blv[c];
            *(float4*)&PS[srow*260 + tau*4 + c*64] = plv[c];
            nr = fmaf(blv[c].x, blv[c].x, nr);
            nr = fmaf(blv[c].y, blv[c].y, nr);
            nr = fmaf(blv[c].z, blv[c].z, nr);
            nr = fmaf(blv[c].w, blv[c].w, nr);
        }
        bsrc += 256; psrc += 256;
        __syncthreads();
        // pred slice into registers (one row, 16 contiguous elems)
        float4 pr[4];
#pragma unroll
        for (int i=0;i<4;i++) pr[i] = *(const float4*)&PS[qq*260 + sb + i*4];
        // 16 bank rows via broadcast reads
#pragma unroll
        for (int j=0;j<16;j++){
            float a = acc[j];
#pragma unroll
            for (int i=0;i<4;i++){
                float4 bv = *(const float4*)&BS[j*260 + sb + i*4];
                a = fmaf(bv.x, pr[i].x, a);
                a = fmaf(bv.y, pr[i].y, a);
                a = fmaf(bv.z, pr[i].z, a);
                a = fmaf(bv.w, pr[i].w, a);
            }
            acc[j] = a;
        }
    }

    // ---- reduce partials across the 16 (w,rep) slices ----
    __syncthreads();
    float* RED = S;            // [slot16][j16][q16]
    const int slot = w*4 + rep;
#pragma unroll
    for (int j=0;j<16;j++) RED[(slot*16 + j)*16 + qq] = acc[j];
    // norm: 16 threads (tau) share row srow; shuffle-reduce within 16-lane groups
#pragma unroll
    for (int m=1;m<16;m<<=1) nr += __shfl_xor(nr, m);
    __syncthreads();
    const int j2 = tid >> 4, q2 = tid & 15;
    float s = 0.0f;
#pragma unroll
    for (int s16=0;s16<16;s16++) s += RED[(s16*16 + j2)*16 + q2];
    dotp[((size_t)kt*528 + jt*16 + j2)*16 + q2] = s;
    if (tau == 0) nrmp[kt*528 + jt*16 + srow] = nr;
}

__global__ void norms_k(const float* __restrict__ nrmp, float* __restrict__ invn){
    int j = blockIdx.x*blockDim.x + threadIdx.x;
    if (j < 528){
        float s = 0.0f;
        for (int kt=0; kt<SKC; kt++) s += nrmp[kt*528 + j];
        invn[j] = 1.0f/(sqrtf(s) + 1e-8f);
    }
}

__global__ void simsfin_k(const float* __restrict__ dotp, const float* __restrict__ invn,
                          float* __restrict__ sims){
    int fid = blockIdx.x*256 + threadIdx.x;
    int j = fid >> 4, q = fid & 15;
    float s = 0.0f;
    for (int kt=0; kt<SKC; kt++) s += dotp[((size_t)kt*528 + j)*16 + q];
    sims[q*528 + j] = s * invn[j] * invn[MM + q];
}

__global__ __launch_bounds__(64)
void topk_k(const float* __restrict__ sims, int* __restrict__ idx){
    const int q = blockIdx.x;
    const int lane = threadIdx.x;
    __shared__ float vals[528];
    for (int j=lane; j<528; j+=64) vals[j] = sims[q*528 + j];
    __syncthreads();
    for (int kk=0; kk<KNN; kk++){
        float bv = -3.0e38f; int bi = 1<<30;
        for (int j=lane; j<528; j+=64){
            float v2 = vals[j];
            if (v2 > bv || (v2 == bv && j < bi)){ bv = v2; bi = j; }
        }
#pragma unroll
        for (int msk=1; msk<64; msk<<=1){
            float ov = __shfl_xor(bv, msk);
            int   oi = __shfl_xor(bi, msk);
            if (ov > bv || (ov == bv && oi < bi)){ bv = ov; bi = oi; }
        }
        if (lane == 0){
            idx[q*KNN + kk] = bi;
            vals[bi] = -3.0e38f;
        }
        __syncthreads();
    }
}

__global__ __launch_bounds__(256)
void fuse_k(const float* __restrict__ pred, const float* __restrict__ bank,
            const int* __restrict__ idx, float* __restrict__ out){
    int u = blockIdx.x*256 + threadIdx.x;
    int b = u / (PN/4);
    int e = (u - b*(PN/4)) * 4;
    int id[KNN];
#pragma unroll
    for (int k2=0;k2<KNN;k2++) id[k2] = idx[b*KNN + k2];
    float4 pv = *(const float4*)(pred + (size_t)b*PN + e);
    float ax = 0.5f*pv.x, ay = 0.5f*pv.y, az = 0.5f*pv.z, aw = 0.5f*pv.w;
#pragma unroll
    for (int k2=0;k2<KNN;k2++){
        const float* rp = (id[k2] < MM) ? (bank + (size_t)id[k2]*PN)
                                        : (pred + (size_t)(id[k2]-MM)*PN);
        float4 rv = *(const float4*)(rp + e);
        ax = fmaf(0.05f, rv.x, ax); ay = fmaf(0.05f, rv.y, ay);
        az = fmaf(0.05f, rv.z, az); aw = fmaf(0.05f, rv.w, aw);
    }
    float4 ov; ov.x=ax; ov.y=ay; ov.z=az; ov.w=aw;
    *(float4*)(out + (size_t)b*PN + e) = ov;
}

// ---------------------------------------------------------------------------
extern "C" void kernel_launch(void* const* d_in, const int* in_sizes, int n_in,
                              void* d_out, int out_size, void* d_ws, size_t ws_size,
                              hipStream_t stream)
{
    (void)in_sizes; (void)n_in; (void)out_size; (void)ws_size;
    const float* x_enc  = (const float*)d_in[0];
    const float* x_mark = (const float*)d_in[1];
    const float* W_emb  = (const float*)d_in[4];
    const float* b_emb  = (const float*)d_in[5];
    const float* Wq  = (const float*)d_in[6];
    const float* Wk  = (const float*)d_in[7];
    const float* Wv  = (const float*)d_in[8];
    const float* Wo  = (const float*)d_in[9];
    const float* bq  = (const float*)d_in[10];
    const float* bk  = (const float*)d_in[11];
    const float* bv_ = (const float*)d_in[12];
    const float* bo  = (const float*)d_in[13];
    const float* ln1w = (const float*)d_in[14];
    const float* ln1b = (const float*)d_in[15];
    const float* ln2w = (const float*)d_in[16];
    const float* ln2b = (const float*)d_in[17];
    const float* Wff1 = (const float*)d_in[18];
    const float* bff1 = (const float*)d_in[19];
    const float* Wff2 = (const float*)d_in[20];
    const float* bff2 = (const float*)d_in[21];
    const float* lnfw = (const float*)d_in[22];
    const float* lnfb = (const float*)d_in[23];
    const float* Wproj = (const float*)d_in[24];
    const float* bproj = (const float*)d_in[25];
    const float* bank  = (const float*)d_in[26];
    float* out = (float*)d_out;

    char* pp = (char*)d_ws;
    auto a16 = [&](size_t elems)->uint16_t*{ uint16_t* r=(uint16_t*)pp; pp += ((elems*2 + 255)/256)*256; return r; };
    auto af  = [&](size_t elems)->float*  { float* r=(float*)pp;  pp += ((elems*4 + 255)/256)*256; return r; };

    uint16_t* wembT_h = a16(262144);        uint16_t* wembT_l = a16(262144);
    uint16_t* wqkvT_h = a16(2*1536*512);    uint16_t* wqkvT_l = a16(2*1536*512);
    uint16_t* woT_h   = a16(2*262144);      uint16_t* woT_l   = a16(2*262144);
    uint16_t* wff1T_h = a16(2*2048*512);    uint16_t* wff1T_l = a16(2*2048*512);
    uint16_t* wff2T_h = a16(2*512*2048);    uint16_t* wff2T_l = a16(2*512*2048);
    uint16_t* wprjT_h = a16(172032);        uint16_t* wprjT_l = a16(172032);
    float*    bqkv    = af(3072);
    uint16_t* hb_h    = a16((size_t)BT*512);
    uint16_t* hb_l    = a16((size_t)BT*512);
    uint16_t* tok_h   = a16((size_t)BT*512);     // og fp32 aliases tok region
    uint16_t* tok_l   = a16((size_t)BT*512);
    float*    og      = (float*)tok_h;
    float*    qb      = af((size_t)BT*512);
    float*    kb      = af((size_t)BT*512);
    float*    vb      = af((size_t)BT*512);
    uint16_t* t1b_h   = a16((size_t)BT*512);
    uint16_t* t1b_l   = a16((size_t)BT*512);
    uint16_t* midb_h  = (uint16_t*)qb;           // mid aliases qb..t1b
    uint16_t* midb_l  = midb_h + (size_t)BT*2048;
    float*    h       = af((size_t)BT*512);
    float*    pred    = af((size_t)BB*PN);
    float*    dotp    = af((size_t)SKC*528*16);
    float*    nrmp    = af(SKC*528);
    float*    invn    = af(528);
    float*    sims    = af(16*528);
    int*      idxp    = (int*)af(256);

    dim3 blk(256);

    // ---- input/weight prep ----
    tok_k<<<dim3(17,16,BB), blk, 0, stream>>>(x_enc, x_mark, tok_h, tok_l);
    wtr_k<<<dim3(16,16,1), blk, 0, stream>>>(W_emb, wembT_h, wembT_l, 512, 512, 262144);
    wtr_k<<<dim3(16,16,2), blk, 0, stream>>>(Wq, wqkvT_h,          wqkvT_l,          512, 512, 786432);
    wtr_k<<<dim3(16,16,2), blk, 0, stream>>>(Wk, wqkvT_h + 262144, wqkvT_l + 262144, 512, 512, 786432);
    wtr_k<<<dim3(16,16,2), blk, 0, stream>>>(Wv, wqkvT_h + 524288, wqkvT_l + 524288, 512, 512, 786432);
    wtr_k<<<dim3(16,16,2), blk, 0, stream>>>(Wo, woT_h, woT_l, 512, 512, 262144);
    wtr_k<<<dim3(64,16,2), blk, 0, stream>>>(Wff1, wff1T_h, wff1T_l, 512, 2048, 1048576);
    wtr_k<<<dim3(16,64,2), blk, 0, stream>>>(Wff2, wff2T_h, wff2T_l, 2048, 512, 1048576);
    wtr_k<<<dim3(11,16,1), blk, 0, stream>>>(Wproj, wprjT_h, wprjT_l, 512, 336, 172032);
    catb_k<<<dim3(12), blk, 0, stream>>>(bq, bk, bv_, bqkv);

    // ---- embedding GEMM ----
    bgemm<64, EPI_F32|EPI_BF16><<<dim3(8,65), blk, 0, stream>>>(
        tok_h, tok_l, wembT_h, wembT_l, b_emb, h, hb_h, hb_l, BT, 512, 512);

    for (int i=0;i<2;i++){
        bgemm<128, EPI_QKV><<<dim3(12,65), blk, 0, stream>>>(
            hb_h, hb_l, wqkvT_h + (size_t)i*786432, wqkvT_l + (size_t)i*786432,
            bqkv + i*1536, qb, nullptr, nullptr, BT, 1536, 512);
        attn_k<<<dim3(9,HH,BB), blk, 0, stream>>>(qb, kb, vb, t1b_h, t1b_l);
        bgemm<64, EPI_F32><<<dim3(8,65), blk, 0, stream>>>(
            t1b_h, t1b_l, woT_h + (size_t)i*262144, woT_l + (size_t)i*262144,
            bo + i*512, og, nullptr, nullptr, BT, 512, 512);
        ln_k<<<BT, blk, 0, stream>>>(h, og, ln1w + i*512, ln1b + i*512, h, hb_h, hb_l);
        bgemm<128, EPI_GELU|EPI_BF16><<<dim3(16,65), blk, 0, stream>>>(
            hb_h, hb_l, wff1T_h + (size_t)i*1048576, wff1T_l + (size_t)i*1048576,
            bff1 + i*DFFN, nullptr, midb_h, midb_l, BT, DFFN, 512);
        bgemm<64, EPI_F32><<<dim3(8,65), blk, 0, stream>>>(
            midb_h, midb_l, wff2T_h + (size_t)i*1048576, wff2T_l + (size_t)i*1048576,
            bff2 + i*512, og, nullptr, nullptr, BT, 512, DFFN);
        ln_k<<<BT, blk, 0, stream>>>(h, og, ln2w + i*512, ln2b + i*512, h, hb_h, hb_l);
    }

    ln_k<<<BT, blk, 0, stream>>>(h, nullptr, lnfw, lnfb, h, hb_h, hb_l);

    bgemm<64, EPI_PREDT><<<dim3(6,65), blk, 0, stream>>>(
        hb_h, hb_l, wprjT_h, wprjT_l, bproj, pred, nullptr, nullptr, BT, PP, 512);

    sims_k<<<dim3(33,SKC), blk, 0, stream>>>(pred, bank, dotp, nrmp);
    norms_k<<<dim3(3), blk, 0, stream>>>(nrmp, invn);
    simsfin_k<<<dim3(33), blk, 0, stream>>>(dotp, invn, sims);
    topk_k<<<dim3(BB), dim3(64), 0, stream>>>(sims, idxp);
    fuse_k<<<dim3((BB*PN/4)/256), blk, 0, stream>>>(pred, bank, idxp, out);
}

// Round 4
// 1375.501 us; speedup vs baseline: 1.1074x; 1.1074x over previous
//
#include <hip/hip_runtime.h>
#include <stdint.h>
#include <math.h>

#define TT 516
#define BB 16
#define DD 512
#define LL 512
#define NN 512
#define HH 8
#define DHD 64
#define DFFN 2048
#define PP 336
#define MM 512
#define KNN 10
#define BT (BB*TT)      /* 8256 */
#define PN (PP*NN)      /* 172032 */
#define SKC 32          /* sims k-chunks */
#define SCHUNK (PN/SKC) /* 5376 */
#define SSTG (SCHUNK/256) /* 21 stages */

using f32x4  = __attribute__((ext_vector_type(4))) float;
using bf16x8 = __attribute__((ext_vector_type(8))) __bf16;
using u16x8  = __attribute__((ext_vector_type(8))) unsigned short;

__device__ __forceinline__ float gelu_tanh(float x){
    float x3 = x*x*x;
    return 0.5f*x*(1.0f + tanhf(0.7978845608028654f*(x + 0.044715f*x3)));
}

__device__ __forceinline__ uint16_t f2bf(float x){
    uint32_t u = __builtin_bit_cast(uint32_t, x);
    uint32_t r = (u + 0x7FFFu + ((u >> 16) & 1u)) >> 16;
    return (uint16_t)r;
}

__device__ __forceinline__ void split_bf(float x, uint16_t& hi, uint16_t& lo){
    uint32_t u  = __builtin_bit_cast(uint32_t, x);
    uint32_t hr = (u + 0x7FFFu + ((u >> 16) & 1u)) & 0xFFFF0000u;
    float hf = __builtin_bit_cast(float, hr);
    hi = (uint16_t)(hr >> 16);
    lo = f2bf(x - hf);
}

__device__ __forceinline__ void gl16(const uint16_t* g, uint16_t* l){
    __builtin_amdgcn_global_load_lds(
        (const __attribute__((address_space(1))) unsigned int*)(const void*)g,
        (__attribute__((address_space(3))) unsigned int*)(void*)l, 16, 0, 0);
}

#define EPI_F32   1
#define EPI_BF16  2
#define EPI_GELU  4
#define EPI_PREDT 8
#define EPI_QKV   16

// ---------------------------------------------------------------------------
// Split-bf16 MFMA GEMM (unchanged)
// ---------------------------------------------------------------------------
template<int BN, int FLAGS>
__global__ __launch_bounds__(256)
void bgemm(const uint16_t* __restrict__ Ah, const uint16_t* __restrict__ Al,
           const uint16_t* __restrict__ Bh, const uint16_t* __restrict__ Bl,
           const float* __restrict__ bias, float* __restrict__ Cf,
           uint16_t* __restrict__ Cbh, uint16_t* __restrict__ Cbl,
           int Msz, int Nsz, int Ksz)
{
    constexpr int FN = BN/32;
    __shared__ uint16_t As0[4096], As1[4096];
    __shared__ uint16_t Bs0[BN*32], Bs1[BN*32];

    const int tid  = threadIdx.x;
    const int lane = tid & 63;
    const int wu   = __builtin_amdgcn_readfirstlane(tid >> 6);
    const int wm   = wu >> 1, wn = wu & 1;
    const int m0   = blockIdx.y * 128;
    const int n0   = blockIdx.x * BN;

    const int r0c = tid >> 2;
    const int cc  = tid & 3;
    const int sw  = (r0c ^ (r0c >> 2)) & 3;
    const int csw = (cc ^ sw) * 8;
    int rA0 = m0 + r0c;      if (rA0 > Msz-1) rA0 = Msz-1;
    int rA1 = m0 + r0c + 64; if (rA1 > Msz-1) rA1 = Msz-1;
    int rB0 = n0 + r0c;      if (rB0 > Nsz-1) rB0 = Nsz-1;
    int rB1 = n0 + r0c + 64; if (rB1 > Nsz-1) rB1 = Nsz-1;
    const uint16_t* pAh0 = Ah + (size_t)rA0*Ksz + csw;
    const uint16_t* pAh1 = Ah + (size_t)rA1*Ksz + csw;
    const uint16_t* pAl0 = Al + (size_t)rA0*Ksz + csw;
    const uint16_t* pAl1 = Al + (size_t)rA1*Ksz + csw;
    const uint16_t* pBh0 = Bh + (size_t)rB0*Ksz + csw;
    const uint16_t* pBh1 = Bh + (size_t)rB1*Ksz + csw;
    const uint16_t* pBl0 = Bl + (size_t)rB0*Ksz + csw;
    const uint16_t* pBl1 = Bl + (size_t)rB1*Ksz + csw;

    f32x4 acc[4][FN];
#pragma unroll
    for (int i=0;i<4;i++)
#pragma unroll
        for (int j=0;j<FN;j++) acc[i][j] = (f32x4){0.f,0.f,0.f,0.f};

    const int lc16  = lane & 15;
    const int slot8 = (((lane>>4) ^ (lane&3) ^ ((lane>>2)&3))) * 8;
    const int rAf   = (wm*64 + lc16) * 32 + slot8;
    const int rBf   = (wn*(BN/2) + lc16) * 32 + slot8;

    for (int kt = 0; kt < Ksz; kt += 32){
        gl16(pAh0 + kt, &As0[wu*512]);
        gl16(pAh1 + kt, &As0[2048 + wu*512]);
        gl16(pAl0 + kt, &As1[wu*512]);
        gl16(pAl1 + kt, &As1[2048 + wu*512]);
        if (BN == 128){
            gl16(pBh0 + kt, &Bs0[wu*512]);
            gl16(pBh1 + kt, &Bs0[2048 + wu*512]);
            gl16(pBl0 + kt, &Bs1[wu*512]);
            gl16(pBl1 + kt, &Bs1[2048 + wu*512]);
        } else {
            gl16(pBh0 + kt, &Bs0[wu*512]);
            gl16(pBl0 + kt, &Bs1[wu*512]);
        }
        __syncthreads();

        bf16x8 ah[4], al[4], bh[FN], bl[FN];
#pragma unroll
        for (int fm=0; fm<4; fm++){
            ah[fm] = __builtin_bit_cast(bf16x8, *(const u16x8*)&As0[rAf + fm*512]);
            al[fm] = __builtin_bit_cast(bf16x8, *(const u16x8*)&As1[rAf + fm*512]);
        }
#pragma unroll
        for (int fn=0; fn<FN; fn++){
            bh[fn] = __builtin_bit_cast(bf16x8, *(const u16x8*)&Bs0[rBf + fn*512]);
            bl[fn] = __builtin_bit_cast(bf16x8, *(const u16x8*)&Bs1[rBf + fn*512]);
        }
#pragma unroll
        for (int fm=0; fm<4; fm++)
#pragma unroll
            for (int fn=0; fn<FN; fn++){
                acc[fm][fn] = __builtin_amdgcn_mfma_f32_16x16x32_bf16(ah[fm], bh[fn], acc[fm][fn], 0,0,0);
                acc[fm][fn] = __builtin_amdgcn_mfma_f32_16x16x32_bf16(ah[fm], bl[fn], acc[fm][fn], 0,0,0);
                acc[fm][fn] = __builtin_amdgcn_mfma_f32_16x16x32_bf16(al[fm], bh[fn], acc[fm][fn], 0,0,0);
            }
        __syncthreads();
    }

    const int lr4 = (lane >> 4) * 4;
#pragma unroll
    for (int fm=0; fm<4; fm++){
        const int rbase = m0 + wm*64 + fm*16 + lr4;
#pragma unroll
        for (int fn=0; fn<FN; fn++){
            const int col = n0 + wn*(BN/2) + fn*16 + lc16;
            f32x4 v = acc[fm][fn];
            if (FLAGS & EPI_PREDT){
#pragma unroll
                for (int r=0;r<4;r++){
                    int row = rbase + r;
                    if (row < Msz && col < PP){
                        int b = row / TT, t = row - b*TT;
                        if (t < NN)
                            Cf[((size_t)b*PP + col)*NN + t] = v[r] + bias[col];
                    }
                }
            } else {
                const float bcol = bias[col];
#pragma unroll
                for (int r=0;r<4;r++){
                    int row = rbase + r;
                    if (row < Msz){
                        float x = v[r] + bcol;
                        if (FLAGS & EPI_GELU) x = gelu_tanh(x);
                        if (FLAGS & EPI_QKV){
                            Cf[(size_t)(col>>9)*((size_t)BT*512) + (size_t)row*512 + (col&511)] = x;
                        } else {
                            if (FLAGS & EPI_F32) Cf[(size_t)row*Nsz + col] = x;
                        }
                        if (FLAGS & EPI_BF16){
                            uint16_t hi, lo; split_bf(x, hi, lo);
                            Cbh[(size_t)row*Nsz + col] = hi;
                            Cbl[(size_t)row*Nsz + col] = lo;
                        }
                    }
                }
            }
        }
    }
}

// ---------------------------------------------------------------------------
// tok transpose + split (unchanged)
// ---------------------------------------------------------------------------
__global__ __launch_bounds__(256)
void tok_k(const float* __restrict__ xe, const float* __restrict__ xm,
           uint16_t* __restrict__ th, uint16_t* __restrict__ tl)
{
    const int b = blockIdx.z;
    const int t0 = blockIdx.x*32, l0 = blockIdx.y*32;
    __shared__ float tile[32][33];
    const int i = threadIdx.x >> 3;
    const int j4 = (threadIdx.x & 7) * 4;
#pragma unroll
    for (int c=0;c<4;c++){
        int t = t0 + j4 + c;
        float v = 0.0f;
        if (t < 512)      v = xe[((size_t)b*LL + l0+i)*NN + t];
        else if (t < 516) v = xm[((size_t)b*LL + l0+i)*4 + (t-512)];
        tile[i][j4+c] = v;
    }
    __syncthreads();
    int t = t0 + i;
    if (t < TT){
#pragma unroll
        for (int c=0;c<4;c++){
            uint16_t hi, lo; split_bf(tile[j4+c][i], hi, lo);
            size_t idx = ((size_t)b*TT + t)*512 + l0 + j4 + c;
            th[idx] = hi; tl[idx] = lo;
        }
    }
}

// ---------------------------------------------------------------------------
// weight transpose-split (unchanged)
// ---------------------------------------------------------------------------
__global__ __launch_bounds__(256)
void wtr_k(const float* __restrict__ src, uint16_t* __restrict__ dh,
           uint16_t* __restrict__ dl, int Ksz, int Nsz, size_t zstride)
{
    const int z = blockIdx.z;
    src += (size_t)z*Ksz*Nsz; dh += (size_t)z*zstride; dl += (size_t)z*zstride;
    __shared__ float tile[32][33];
    const int kt = blockIdx.y*32, nt = blockIdx.x*32;
    const int i = threadIdx.x >> 3;
    const int j4 = (threadIdx.x & 7) * 4;
#pragma unroll
    for (int c=0;c<4;c++){
        int n = nt + j4 + c;
        tile[i][j4+c] = (n < Nsz) ? src[(size_t)(kt+i)*Nsz + n] : 0.0f;
    }
    __syncthreads();
    int n = nt + i;
    if (n < Nsz){
#pragma unroll
        for (int c=0;c<4;c++){
            uint16_t hi, lo; split_bf(tile[j4+c][i], hi, lo);
            size_t idx = (size_t)n*Ksz + kt + j4 + c;
            dh[idx] = hi; dl[idx] = lo;
        }
    }
}

__global__ void catb_k(const float* __restrict__ bq, const float* __restrict__ bk,
                       const float* __restrict__ bv, float* __restrict__ dst){
    int j = blockIdx.x*256 + threadIdx.x;
    if (j >= 3072) return;
    int layer = j / 1536, r = j - layer*1536;
    float v;
    if (r < 512)       v = bq[layer*512 + r];
    else if (r < 1024) v = bk[layer*512 + r - 512];
    else               v = bv[layer*512 + r - 1024];
    dst[j] = v;
}

// ---------------------------------------------------------------------------
// Flash-style fp32 attention (unchanged)
// ---------------------------------------------------------------------------
__global__ __launch_bounds__(256)
void attn_k(const float* __restrict__ q, const float* __restrict__ k,
            const float* __restrict__ v, uint16_t* __restrict__ oh,
            uint16_t* __restrict__ ol)
{
    const int tt = blockIdx.x;
    const int h  = blockIdx.y;
    const int b  = blockIdx.z;
    const int t0 = tt * 64;
    const int tid = threadIdx.x;
    const int ty = tid >> 4, tx = tid & 15;
    const int ty4 = ty*4, tx4 = tx*4;

    __shared__ float QT[64][68];
    __shared__ float KT[64][68];
    __shared__ float Vs[64][68];
    __shared__ float PT[64][68];

    {
        int r  = tid >> 2;
        int dc = (tid & 3) * 16;
        int t  = t0 + r;
#pragma unroll
        for (int c=0;c<4;c++){
            float4 val;
            if (t < TT) val = *(const float4*)(q + ((size_t)(b*TT + t))*DD + h*DHD + dc + 4*c);
            else { val.x=val.y=val.z=val.w=0.0f; }
            QT[dc+4*c+0][r] = val.x; QT[dc+4*c+1][r] = val.y;
            QT[dc+4*c+2][r] = val.z; QT[dc+4*c+3][r] = val.w;
        }
    }

    float accO[4][4];
    float mrow[4], lrow[4];
#pragma unroll
    for (int i=0;i<4;i++){
        mrow[i] = -1e30f; lrow[i] = 0.0f;
#pragma unroll
        for (int j=0;j<4;j++) accO[i][j] = 0.0f;
    }
    const float scale = 0.125f;

    for (int st=0; st<9; st++){
        int s0 = st*64;
        __syncthreads();
        {
            int r  = tid >> 2;
            int dc = (tid & 3) * 16;
            int s  = s0 + r;
#pragma unroll
            for (int c=0;c<4;c++){
                float4 kv, vv;
                if (s < TT){
                    kv = *(const float4*)(k + ((size_t)(b*TT + s))*DD + h*DHD + dc + 4*c);
                    vv = *(const float4*)(v + ((size_t)(b*TT + s))*DD + h*DHD + dc + 4*c);
                } else { kv.x=kv.y=kv.z=kv.w=0.0f; vv.x=vv.y=vv.z=vv.w=0.0f; }
                KT[dc+4*c+0][r] = kv.x; KT[dc+4*c+1][r] = kv.y;
                KT[dc+4*c+2][r] = kv.z; KT[dc+4*c+3][r] = kv.w;
                *(float4*)&Vs[r][dc+4*c] = vv;
            }
        }
        __syncthreads();
        float sacc[4][4];
#pragma unroll
        for (int i=0;i<4;i++)
#pragma unroll
            for (int j=0;j<4;j++) sacc[i][j] = 0.0f;
#pragma unroll 8
        for (int d=0; d<64; d++){
            float4 av = *(const float4*)&QT[d][ty4];
            float4 bv = *(const float4*)&KT[d][tx4];
            float a[4] = {av.x, av.y, av.z, av.w};
            float bb2[4] = {bv.x, bv.y, bv.z, bv.w};
#pragma unroll
            for (int i=0;i<4;i++)
#pragma unroll
                for (int j=0;j<4;j++)
                    sacc[i][j] = fmaf(a[i], bb2[j], sacc[i][j]);
        }
        float p[4][4];
#pragma unroll
        for (int i=0;i<4;i++){
            float mx = -1e30f;
#pragma unroll
            for (int j=0;j<4;j++){
                float sv = sacc[i][j]*scale;
                if (s0 + tx4 + j >= TT) sv = -1e30f;
                p[i][j] = sv;
                mx = fmaxf(mx, sv);
            }
#pragma unroll
            for (int msk=1; msk<16; msk<<=1) mx = fmaxf(mx, __shfl_xor(mx, msk));
            float mnew  = fmaxf(mrow[i], mx);
            float alpha = __expf(mrow[i] - mnew);
            mrow[i] = mnew;
            float rs = 0.0f;
#pragma unroll
            for (int j=0;j<4;j++){
                float e = __expf(p[i][j] - mnew);
                p[i][j] = e;
                rs += e;
            }
#pragma unroll
            for (int msk=1; msk<16; msk<<=1) rs += __shfl_xor(rs, msk);
            lrow[i] = lrow[i]*alpha + rs;
#pragma unroll
            for (int j=0;j<4;j++) accO[i][j] *= alpha;
        }
#pragma unroll
        for (int j=0;j<4;j++)
#pragma unroll
            for (int i=0;i<4;i++)
                PT[tx4+j][ty4+i] = p[i][j];
        __syncthreads();
#pragma unroll 8
        for (int s=0; s<64; s++){
            float4 pa = *(const float4*)&PT[s][ty4];
            float4 vb = *(const float4*)&Vs[s][tx4];
            float a[4] = {pa.x, pa.y, pa.z, pa.w};
            float bb2[4] = {vb.x, vb.y, vb.z, vb.w};
#pragma unroll
            for (int i=0;i<4;i++)
#pragma unroll
                for (int j=0;j<4;j++)
                    accO[i][j] = fmaf(a[i], bb2[j], accO[i][j]);
        }
    }
#pragma unroll
    for (int i=0;i<4;i++){
        int t = t0 + ty4 + i;
        if (t < TT){
            float inv = 1.0f/lrow[i];
            size_t base = ((size_t)(b*TT + t))*DD + h*DHD + tx4;
#pragma unroll
            for (int j=0;j<4;j++){
                uint16_t hi, lo; split_bf(accO[i][j]*inv, hi, lo);
                oh[base + j] = hi; ol[base + j] = lo;
            }
        }
    }
}

// ---------------------------------------------------------------------------
// Residual + LayerNorm (unchanged)
// ---------------------------------------------------------------------------
__global__ __launch_bounds__(256)
void ln_k(const float* __restrict__ src, const float* __restrict__ res,
          const float* __restrict__ w, const float* __restrict__ bia,
          float* __restrict__ dst, uint16_t* __restrict__ dbh,
          uint16_t* __restrict__ dbl)
{
    const int r = blockIdx.x;
    const int tid = threadIdx.x;
    const float* sp = src + (size_t)r*DD;
    float x0 = sp[tid], x1 = sp[tid + 256];
    if (res){
        x0 += res[(size_t)r*DD + tid];
        x1 += res[(size_t)r*DD + tid + 256];
    }
    float s  = x0 + x1;
    float sq = x0*x0 + x1*x1;
#pragma unroll
    for (int msk=1; msk<64; msk<<=1){
        s  += __shfl_xor(s,  msk);
        sq += __shfl_xor(sq, msk);
    }
    __shared__ float sm[8];
    int wv = tid >> 6, ln = tid & 63;
    if (ln == 0){ sm[wv] = s; sm[wv+4] = sq; }
    __syncthreads();
    s  = sm[0]+sm[1]+sm[2]+sm[3];
    sq = sm[4]+sm[5]+sm[6]+sm[7];
    float mu  = s * (1.0f/512.0f);
    float var = sq * (1.0f/512.0f) - mu*mu;
    float rsd = rsqrtf(var + 1e-5f);
    float y0 = (x0 - mu)*rsd*w[tid]       + bia[tid];
    float y1 = (x1 - mu)*rsd*w[tid + 256] + bia[tid + 256];
    dst[(size_t)r*DD + tid]       = y0;
    dst[(size_t)r*DD + tid + 256] = y1;
    uint16_t hi, lo;
    split_bf(y0, hi, lo); dbh[(size_t)r*DD + tid] = hi;       dbl[(size_t)r*DD + tid] = lo;
    split_bf(y1, hi, lo); dbh[(size_t)r*DD + tid + 256] = hi; dbl[(size_t)r*DD + tid + 256] = lo;
}

// ---------------------------------------------------------------------------
// sims v2: no spill (launch_bounds cap 256 VGPR), pred slices direct from
// global (L2-resident), bank tile broadcast from LDS. Deterministic split-K.
// ---------------------------------------------------------------------------
__global__ __launch_bounds__(256, 2)
void sims_k(const float* __restrict__ pred, const float* __restrict__ bank,
            float* __restrict__ dotp, float* __restrict__ nrmp)
{
    const int jt = blockIdx.x, kt = blockIdx.y;
    const int tid  = threadIdx.x;
    const int lane = tid & 63;
    const int w    = tid >> 6;
    const int qq   = lane & 15;
    const int rep  = lane >> 4;           // 0..3
    const int sb   = (w*4 + rep)*16;      // elem slice base within 256-elem stage
    const int srow = tid >> 4;            // staging row 0..15
    const int tau  = tid & 15;

    __shared__ float BS[16*264];          // bank tile, stride 264 floats

    const int jr = jt*16 + srow;
    const float* bsrc = (jr < MM) ? (bank + (size_t)jr*PN)
                                  : (pred + (size_t)(jr - MM)*PN);
    bsrc += (size_t)kt*SCHUNK + tau*4;
    const float* psrc = pred + (size_t)qq*PN + (size_t)kt*SCHUNK + sb;

    float acc[16];
#pragma unroll
    for (int j=0;j<16;j++) acc[j] = 0.0f;
    float nr = 0.0f;

    for (int st=0; st<SSTG; ++st){
        float4 blv[4];
#pragma unroll
        for (int c=0;c<4;c++) blv[c] = *(const float4*)(bsrc + c*64);
        float4 pr[4];
#pragma unroll
        for (int i=0;i<4;i++) pr[i] = *(const float4*)(psrc + i*4);
        __syncthreads();   // previous stage's compute done before overwrite
#pragma unroll
        for (int c=0;c<4;c++){
            *(float4*)&BS[srow*264 + tau*4 + c*64] = blv[c];
            nr = fmaf(blv[c].x, blv[c].x, nr);
            nr = fmaf(blv[c].y, blv[c].y, nr);
            nr = fmaf(blv[c].z, blv[c].z, nr);
            nr = fmaf(blv[c].w, blv[c].w, nr);
        }
        __syncthreads();
#pragma unroll
        for (int j=0;j<16;j++){
            float a = acc[j];
#pragma unroll
            for (int i=0;i<4;i++){
                float4 bv = *(const float4*)&BS[j*264 + sb + i*4];
                a = fmaf(bv.x, pr[i].x, a);
                a = fmaf(bv.y, pr[i].y, a);
                a = fmaf(bv.z, pr[i].z, a);
                a = fmaf(bv.w, pr[i].w, a);
            }
            acc[j] = a;
        }
        bsrc += 256; psrc += 256;
    }

    // ---- reduce partials across the 16 (w,rep) slices ----
    __syncthreads();
    float* RED = BS;           // [slot16][j16][q16]  (4096 <= 4224)
    const int slot = w*4 + rep;
#pragma unroll
    for (int j=0;j<16;j++) RED[(slot*16 + j)*16 + qq] = acc[j];
#pragma unroll
    for (int m=1;m<16;m<<=1) nr += __shfl_xor(nr, m);
    __syncthreads();
    const int j2 = tid >> 4, q2 = tid & 15;
    float s = 0.0f;
#pragma unroll
    for (int s16=0;s16<16;s16++) s += RED[(s16*16 + j2)*16 + q2];
    dotp[((size_t)kt*528 + jt*16 + j2)*16 + q2] = s;
    if (tau == 0) nrmp[kt*528 + jt*16 + srow] = nr;
}

__global__ void norms_k(const float* __restrict__ nrmp, float* __restrict__ invn){
    int j = blockIdx.x*blockDim.x + threadIdx.x;
    if (j < 528){
        float s = 0.0f;
        for (int kt=0; kt<SKC; kt++) s += nrmp[kt*528 + j];
        invn[j] = 1.0f/(sqrtf(s) + 1e-8f);
    }
}

__global__ void simsfin_k(const float* __restrict__ dotp, const float* __restrict__ invn,
                          float* __restrict__ sims){
    int fid = blockIdx.x*256 + threadIdx.x;
    int j = fid >> 4, q = fid & 15;
    float s = 0.0f;
    for (int kt=0; kt<SKC; kt++) s += dotp[((size_t)kt*528 + j)*16 + q];
    sims[q*528 + j] = s * invn[j] * invn[MM + q];
}

__global__ __launch_bounds__(64)
void topk_k(const float* __restrict__ sims, int* __restrict__ idx){
    const int q = blockIdx.x;
    const int lane = threadIdx.x;
    __shared__ float vals[528];
    for (int j=lane; j<528; j+=64) vals[j] = sims[q*528 + j];
    __syncthreads();
    for (int kk=0; kk<KNN; kk++){
        float bv = -3.0e38f; int bi = 1<<30;
        for (int j=lane; j<528; j+=64){
            float v2 = vals[j];
            if (v2 > bv || (v2 == bv && j < bi)){ bv = v2; bi = j; }
        }
#pragma unroll
        for (int msk=1; msk<64; msk<<=1){
            float ov = __shfl_xor(bv, msk);
            int   oi = __shfl_xor(bi, msk);
            if (ov > bv || (ov == bv && oi < bi)){ bv = ov; bi = oi; }
        }
        if (lane == 0){
            idx[q*KNN + kk] = bi;
            vals[bi] = -3.0e38f;
        }
        __syncthreads();
    }
}

__global__ __launch_bounds__(256)
void fuse_k(const float* __restrict__ pred, const float* __restrict__ bank,
            const int* __restrict__ idx, float* __restrict__ out){
    int u = blockIdx.x*256 + threadIdx.x;
    int b = u / (PN/4);
    int e = (u - b*(PN/4)) * 4;
    int id[KNN];
#pragma unroll
    for (int k2=0;k2<KNN;k2++) id[k2] = idx[b*KNN + k2];
    float4 pv = *(const float4*)(pred + (size_t)b*PN + e);
    float ax = 0.5f*pv.x, ay = 0.5f*pv.y, az = 0.5f*pv.z, aw = 0.5f*pv.w;
#pragma unroll
    for (int k2=0;k2<KNN;k2++){
        const float* rp = (id[k2] < MM) ? (bank + (size_t)id[k2]*PN)
                                        : (pred + (size_t)(id[k2]-MM)*PN);
        float4 rv = *(const float4*)(rp + e);
        ax = fmaf(0.05f, rv.x, ax); ay = fmaf(0.05f, rv.y, ay);
        az = fmaf(0.05f, rv.z, az); aw = fmaf(0.05f, rv.w, aw);
    }
    float4 ov; ov.x=ax; ov.y=ay; ov.z=az; ov.w=aw;
    *(float4*)(out + (size_t)b*PN + e) = ov;
}

// ---------------------------------------------------------------------------
extern "C" void kernel_launch(void* const* d_in, const int* in_sizes, int n_in,
                              void* d_out, int out_size, void* d_ws, size_t ws_size,
                              hipStream_t stream)
{
    (void)in_sizes; (void)n_in; (void)out_size; (void)ws_size;
    const float* x_enc  = (const float*)d_in[0];
    const float* x_mark = (const float*)d_in[1];
    const float* W_emb  = (const float*)d_in[4];
    const float* b_emb  = (const float*)d_in[5];
    const float* Wq  = (const float*)d_in[6];
    const float* Wk  = (const float*)d_in[7];
    const float* Wv  = (const float*)d_in[8];
    const float* Wo  = (const float*)d_in[9];
    const float* bq  = (const float*)d_in[10];
    const float* bk  = (const float*)d_in[11];
    const float* bv_ = (const float*)d_in[12];
    const float* bo  = (const float*)d_in[13];
    const float* ln1w = (const float*)d_in[14];
    const float* ln1b = (const float*)d_in[15];
    const float* ln2w = (const float*)d_in[16];
    const float* ln2b = (const float*)d_in[17];
    const float* Wff1 = (const float*)d_in[18];
    const float* bff1 = (const float*)d_in[19];
    const float* Wff2 = (const float*)d_in[20];
    const float* bff2 = (const float*)d_in[21];
    const float* lnfw = (const float*)d_in[22];
    const float* lnfb = (const float*)d_in[23];
    const float* Wproj = (const float*)d_in[24];
    const float* bproj = (const float*)d_in[25];
    const float* bank  = (const float*)d_in[26];
    float* out = (float*)d_out;

    char* pp = (char*)d_ws;
    auto a16 = [&](size_t elems)->uint16_t*{ uint16_t* r=(uint16_t*)pp; pp += ((elems*2 + 255)/256)*256; return r; };
    auto af  = [&](size_t elems)->float*  { float* r=(float*)pp;  pp += ((elems*4 + 255)/256)*256; return r; };

    uint16_t* wembT_h = a16(262144);        uint16_t* wembT_l = a16(262144);
    uint16_t* wqkvT_h = a16(2*1536*512);    uint16_t* wqkvT_l = a16(2*1536*512);
    uint16_t* woT_h   = a16(2*262144);      uint16_t* woT_l   = a16(2*262144);
    uint16_t* wff1T_h = a16(2*2048*512);    uint16_t* wff1T_l = a16(2*2048*512);
    uint16_t* wff2T_h = a16(2*512*2048);    uint16_t* wff2T_l = a16(2*512*2048);
    uint16_t* wprjT_h = a16(172032);        uint16_t* wprjT_l = a16(172032);
    float*    bqkv    = af(3072);
    uint16_t* hb_h    = a16((size_t)BT*512);
    uint16_t* hb_l    = a16((size_t)BT*512);
    uint16_t* tok_h   = a16((size_t)BT*512);     // og fp32 aliases tok region
    uint16_t* tok_l   = a16((size_t)BT*512);
    float*    og      = (float*)tok_h;
    float*    qb      = af((size_t)BT*512);
    float*    kb      = af((size_t)BT*512);
    float*    vb      = af((size_t)BT*512);
    uint16_t* t1b_h   = a16((size_t)BT*512);
    uint16_t* t1b_l   = a16((size_t)BT*512);
    uint16_t* midb_h  = (uint16_t*)qb;           // mid aliases qb..t1b
    uint16_t* midb_l  = midb_h + (size_t)BT*2048;
    float*    h       = af((size_t)BT*512);
    float*    pred    = af((size_t)BB*PN);
    float*    dotp    = af((size_t)SKC*528*16);
    float*    nrmp    = af(SKC*528);
    float*    invn    = af(528);
    float*    sims    = af(16*528);
    int*      idxp    = (int*)af(256);

    dim3 blk(256);

    // ---- input/weight prep ----
    tok_k<<<dim3(17,16,BB), blk, 0, stream>>>(x_enc, x_mark, tok_h, tok_l);
    wtr_k<<<dim3(16,16,1), blk, 0, stream>>>(W_emb, wembT_h, wembT_l, 512, 512, 262144);
    wtr_k<<<dim3(16,16,2), blk, 0, stream>>>(Wq, wqkvT_h,          wqkvT_l,          512, 512, 786432);
    wtr_k<<<dim3(16,16,2), blk, 0, stream>>>(Wk, wqkvT_h + 262144, wqkvT_l + 262144, 512, 512, 786432);
    wtr_k<<<dim3(16,16,2), blk, 0, stream>>>(Wv, wqkvT_h + 524288, wqkvT_l + 524288, 512, 512, 786432);
    wtr_k<<<dim3(16,16,2), blk, 0, stream>>>(Wo, woT_h, woT_l, 512, 512, 262144);
    wtr_k<<<dim3(64,16,2), blk, 0, stream>>>(Wff1, wff1T_h, wff1T_l, 512, 2048, 1048576);
    wtr_k<<<dim3(16,64,2), blk, 0, stream>>>(Wff2, wff2T_h, wff2T_l, 2048, 512, 1048576);
    wtr_k<<<dim3(11,16,1), blk, 0, stream>>>(Wproj, wprjT_h, wprjT_l, 512, 336, 172032);
    catb_k<<<dim3(12), blk, 0, stream>>>(bq, bk, bv_, bqkv);

    // ---- embedding GEMM ----
    bgemm<64, EPI_F32|EPI_BF16><<<dim3(8,65), blk, 0, stream>>>(
        tok_h, tok_l, wembT_h, wembT_l, b_emb, h, hb_h, hb_l, BT, 512, 512);

    for (int i=0;i<2;i++){
        bgemm<128, EPI_QKV><<<dim3(12,65), blk, 0, stream>>>(
            hb_h, hb_l, wqkvT_h + (size_t)i*786432, wqkvT_l + (size_t)i*786432,
            bqkv + i*1536, qb, nullptr, nullptr, BT, 1536, 512);
        attn_k<<<dim3(9,HH,BB), blk, 0, stream>>>(qb, kb, vb, t1b_h, t1b_l);
        bgemm<64, EPI_F32><<<dim3(8,65), blk, 0, stream>>>(
            t1b_h, t1b_l, woT_h + (size_t)i*262144, woT_l + (size_t)i*262144,
            bo + i*512, og, nullptr, nullptr, BT, 512, 512);
        ln_k<<<BT, blk, 0, stream>>>(h, og, ln1w + i*512, ln1b + i*512, h, hb_h, hb_l);
        bgemm<128, EPI_GELU|EPI_BF16><<<dim3(16,65), blk, 0, stream>>>(
            hb_h, hb_l, wff1T_h + (size_t)i*1048576, wff1T_l + (size_t)i*1048576,
            bff1 + i*DFFN, nullptr, midb_h, midb_l, BT, DFFN, 512);
        bgemm<64, EPI_F32><<<dim3(8,65), blk, 0, stream>>>(
            midb_h, midb_l, wff2T_h + (size_t)i*1048576, wff2T_l + (size_t)i*1048576,
            bff2 + i*512, og, nullptr, nullptr, BT, 512, DFFN);
        ln_k<<<BT, blk, 0, stream>>>(h, og, ln2w + i*512, ln2b + i*512, h, hb_h, hb_l);
    }

    ln_k<<<BT, blk, 0, stream>>>(h, nullptr, lnfw, lnfb, h, hb_h, hb_l);

    bgemm<64, EPI_PREDT><<<dim3(6,65), blk, 0, stream>>>(
        hb_h, hb_l, wprjT_h, wprjT_l, bproj, pred, nullptr, nullptr, BT, PP, 512);

    sims_k<<<dim3(33,SKC), blk, 0, stream>>>(pred, bank, dotp, nrmp);
    norms_k<<<dim3(3), blk, 0, stream>>>(nrmp, invn);
    simsfin_k<<<dim3(33), blk, 0, stream>>>(dotp, invn, sims);
    topk_k<<<dim3(BB), dim3(64), 0, stream>>>(sims, idxp);
    fuse_k<<<dim3((BB*PN/4)/256), blk, 0, stream>>>(pred, bank, idxp, out);
}

// Round 5
// 1169.423 us; speedup vs baseline: 1.3025x; 1.1762x over previous
//
#include <hip/hip_runtime.h>
#include <stdint.h>
#include <math.h>

#define TT 516
#define BB 16
#define DD 512
#define LL 512
#define NN 512
#define HH 8
#define DHD 64
#define DFFN 2048
#define PP 336
#define MM 512
#define KNN 10
#define BT (BB*TT)      /* 8256 */
#define PN (PP*NN)      /* 172032 */
#define SKC 32          /* sims k-chunks */
#define SCHUNK (PN/SKC) /* 5376 */
#define SSTG (SCHUNK/256) /* 21 stages */
#define VSTR 528        /* transposed-V row stride (uint16 elems) */

using f32x4  = __attribute__((ext_vector_type(4))) float;
using bf16x8 = __attribute__((ext_vector_type(8))) __bf16;
using u16x8  = __attribute__((ext_vector_type(8))) unsigned short;

__device__ __forceinline__ float gelu_tanh(float x){
    float x3 = x*x*x;
    return 0.5f*x*(1.0f + tanhf(0.7978845608028654f*(x + 0.044715f*x3)));
}

__device__ __forceinline__ uint16_t f2bf(float x){
    uint32_t u = __builtin_bit_cast(uint32_t, x);
    uint32_t r = (u + 0x7FFFu + ((u >> 16) & 1u)) >> 16;
    return (uint16_t)r;
}

__device__ __forceinline__ void split_bf(float x, uint16_t& hi, uint16_t& lo){
    uint32_t u  = __builtin_bit_cast(uint32_t, x);
    uint32_t hr = (u + 0x7FFFu + ((u >> 16) & 1u)) & 0xFFFF0000u;
    float hf = __builtin_bit_cast(float, hr);
    hi = (uint16_t)(hr >> 16);
    lo = f2bf(x - hf);
}

__device__ __forceinline__ void gl16(const uint16_t* g, uint16_t* l){
    __builtin_amdgcn_global_load_lds(
        (const __attribute__((address_space(1))) unsigned int*)(const void*)g,
        (__attribute__((address_space(3))) unsigned int*)(void*)l, 16, 0, 0);
}

__device__ __forceinline__ bf16x8 ldb8(const uint16_t* p){
    return __builtin_bit_cast(bf16x8, *(const u16x8*)p);
}

#define EPI_F32   1
#define EPI_BF16  2
#define EPI_GELU  4
#define EPI_PREDT 8
#define EPI_QKV   16

// ---------------------------------------------------------------------------
// Split-bf16 MFMA GEMM. EPI_QKV writes q/k head-major + v transposed, all
// split-bf16, for the MFMA attention kernel.
// ---------------------------------------------------------------------------
template<int BN, int FLAGS>
__global__ __launch_bounds__(256)
void bgemm(const uint16_t* __restrict__ Ah, const uint16_t* __restrict__ Al,
           const uint16_t* __restrict__ Bh, const uint16_t* __restrict__ Bl,
           const float* __restrict__ bias, float* __restrict__ Cf,
           uint16_t* __restrict__ Cbh, uint16_t* __restrict__ Cbl,
           uint16_t* __restrict__ Xkh, uint16_t* __restrict__ Xkl,
           uint16_t* __restrict__ Xvh, uint16_t* __restrict__ Xvl,
           int Msz, int Nsz, int Ksz)
{
    constexpr int FN = BN/32;
    __shared__ uint16_t As0[4096], As1[4096];
    __shared__ uint16_t Bs0[BN*32], Bs1[BN*32];

    const int tid  = threadIdx.x;
    const int lane = tid & 63;
    const int wu   = __builtin_amdgcn_readfirstlane(tid >> 6);
    const int wm   = wu >> 1, wn = wu & 1;
    const int m0   = blockIdx.y * 128;
    const int n0   = blockIdx.x * BN;

    const int r0c = tid >> 2;
    const int cc  = tid & 3;
    const int sw  = (r0c ^ (r0c >> 2)) & 3;
    const int csw = (cc ^ sw) * 8;
    int rA0 = m0 + r0c;      if (rA0 > Msz-1) rA0 = Msz-1;
    int rA1 = m0 + r0c + 64; if (rA1 > Msz-1) rA1 = Msz-1;
    int rB0 = n0 + r0c;      if (rB0 > Nsz-1) rB0 = Nsz-1;
    int rB1 = n0 + r0c + 64; if (rB1 > Nsz-1) rB1 = Nsz-1;
    const uint16_t* pAh0 = Ah + (size_t)rA0*Ksz + csw;
    const uint16_t* pAh1 = Ah + (size_t)rA1*Ksz + csw;
    const uint16_t* pAl0 = Al + (size_t)rA0*Ksz + csw;
    const uint16_t* pAl1 = Al + (size_t)rA1*Ksz + csw;
    const uint16_t* pBh0 = Bh + (size_t)rB0*Ksz + csw;
    const uint16_t* pBh1 = Bh + (size_t)rB1*Ksz + csw;
    const uint16_t* pBl0 = Bl + (size_t)rB0*Ksz + csw;
    const uint16_t* pBl1 = Bl + (size_t)rB1*Ksz + csw;

    f32x4 acc[4][FN];
#pragma unroll
    for (int i=0;i<4;i++)
#pragma unroll
        for (int j=0;j<FN;j++) acc[i][j] = (f32x4){0.f,0.f,0.f,0.f};

    const int lc16  = lane & 15;
    const int slot8 = (((lane>>4) ^ (lane&3) ^ ((lane>>2)&3))) * 8;
    const int rAf   = (wm*64 + lc16) * 32 + slot8;
    const int rBf   = (wn*(BN/2) + lc16) * 32 + slot8;

    for (int kt = 0; kt < Ksz; kt += 32){
        gl16(pAh0 + kt, &As0[wu*512]);
        gl16(pAh1 + kt, &As0[2048 + wu*512]);
        gl16(pAl0 + kt, &As1[wu*512]);
        gl16(pAl1 + kt, &As1[2048 + wu*512]);
        if (BN == 128){
            gl16(pBh0 + kt, &Bs0[wu*512]);
            gl16(pBh1 + kt, &Bs0[2048 + wu*512]);
            gl16(pBl0 + kt, &Bs1[wu*512]);
            gl16(pBl1 + kt, &Bs1[2048 + wu*512]);
        } else {
            gl16(pBh0 + kt, &Bs0[wu*512]);
            gl16(pBl0 + kt, &Bs1[wu*512]);
        }
        __syncthreads();

        bf16x8 ah[4], al[4], bh[FN], bl[FN];
#pragma unroll
        for (int fm=0; fm<4; fm++){
            ah[fm] = ldb8(&As0[rAf + fm*512]);
            al[fm] = ldb8(&As1[rAf + fm*512]);
        }
#pragma unroll
        for (int fn=0; fn<FN; fn++){
            bh[fn] = ldb8(&Bs0[rBf + fn*512]);
            bl[fn] = ldb8(&Bs1[rBf + fn*512]);
        }
#pragma unroll
        for (int fm=0; fm<4; fm++)
#pragma unroll
            for (int fn=0; fn<FN; fn++){
                acc[fm][fn] = __builtin_amdgcn_mfma_f32_16x16x32_bf16(ah[fm], bh[fn], acc[fm][fn], 0,0,0);
                acc[fm][fn] = __builtin_amdgcn_mfma_f32_16x16x32_bf16(ah[fm], bl[fn], acc[fm][fn], 0,0,0);
                acc[fm][fn] = __builtin_amdgcn_mfma_f32_16x16x32_bf16(al[fm], bh[fn], acc[fm][fn], 0,0,0);
            }
        __syncthreads();
    }

    const int lr4 = (lane >> 4) * 4;
#pragma unroll
    for (int fm=0; fm<4; fm++){
        const int rbase = m0 + wm*64 + fm*16 + lr4;
#pragma unroll
        for (int fn=0; fn<FN; fn++){
            const int col = n0 + wn*(BN/2) + fn*16 + lc16;
            f32x4 v = acc[fm][fn];
            if (FLAGS & EPI_PREDT){
#pragma unroll
                for (int r=0;r<4;r++){
                    int row = rbase + r;
                    if (row < Msz && col < PP){
                        int b = row / TT, t = row - b*TT;
                        if (t < NN)
                            Cf[((size_t)b*PP + col)*NN + t] = v[r] + bias[col];
                    }
                }
            } else if (FLAGS & EPI_QKV){
                const int g   = col >> 9;
                const int cc2 = col & 511;
                const int hh2 = cc2 >> 6, dd2 = cc2 & 63;
                const float bcol = bias[col];
#pragma unroll
                for (int r=0;r<4;r++){
                    int row = rbase + r;
                    if (row < Msz){
                        float x = v[r] + bcol;
                        int b2 = row / TT, t2 = row - b2*TT;
                        int bh2 = b2*HH + hh2;
                        uint16_t hi, lo; split_bf(x, hi, lo);
                        if (g == 0){
                            size_t o = ((size_t)bh2*TT + t2)*64 + dd2;
                            Cbh[o] = hi; Cbl[o] = lo;
                        } else if (g == 1){
                            size_t o = ((size_t)bh2*TT + t2)*64 + dd2;
                            Xkh[o] = hi; Xkl[o] = lo;
                        } else {
                            size_t o = ((size_t)bh2*64 + dd2)*VSTR + t2;
                            Xvh[o] = hi; Xvl[o] = lo;
                        }
                    }
                }
            } else {
                const float bcol = bias[col];
#pragma unroll
                for (int r=0;r<4;r++){
                    int row = rbase + r;
                    if (row < Msz){
                        float x = v[r] + bcol;
                        if (FLAGS & EPI_GELU) x = gelu_tanh(x);
                        if (FLAGS & EPI_F32) Cf[(size_t)row*Nsz + col] = x;
                        if (FLAGS & EPI_BF16){
                            uint16_t hi, lo; split_bf(x, hi, lo);
                            Cbh[(size_t)row*Nsz + col] = hi;
                            Cbl[(size_t)row*Nsz + col] = lo;
                        }
                    }
                }
            }
        }
    }
}

// ---------------------------------------------------------------------------
// tok transpose + split (unchanged)
// ---------------------------------------------------------------------------
__global__ __launch_bounds__(256)
void tok_k(const float* __restrict__ xe, const float* __restrict__ xm,
           uint16_t* __restrict__ th, uint16_t* __restrict__ tl)
{
    const int b = blockIdx.z;
    const int t0 = blockIdx.x*32, l0 = blockIdx.y*32;
    __shared__ float tile[32][33];
    const int i = threadIdx.x >> 3;
    const int j4 = (threadIdx.x & 7) * 4;
#pragma unroll
    for (int c=0;c<4;c++){
        int t = t0 + j4 + c;
        float v = 0.0f;
        if (t < 512)      v = xe[((size_t)b*LL + l0+i)*NN + t];
        else if (t < 516) v = xm[((size_t)b*LL + l0+i)*4 + (t-512)];
        tile[i][j4+c] = v;
    }
    __syncthreads();
    int t = t0 + i;
    if (t < TT){
#pragma unroll
        for (int c=0;c<4;c++){
            uint16_t hi, lo; split_bf(tile[j4+c][i], hi, lo);
            size_t idx = ((size_t)b*TT + t)*512 + l0 + j4 + c;
            th[idx] = hi; tl[idx] = lo;
        }
    }
}

// ---------------------------------------------------------------------------
// weight transpose-split (unchanged)
// ---------------------------------------------------------------------------
__global__ __launch_bounds__(256)
void wtr_k(const float* __restrict__ src, uint16_t* __restrict__ dh,
           uint16_t* __restrict__ dl, int Ksz, int Nsz, size_t zstride)
{
    const int z = blockIdx.z;
    src += (size_t)z*Ksz*Nsz; dh += (size_t)z*zstride; dl += (size_t)z*zstride;
    __shared__ float tile[32][33];
    const int kt = blockIdx.y*32, nt = blockIdx.x*32;
    const int i = threadIdx.x >> 3;
    const int j4 = (threadIdx.x & 7) * 4;
#pragma unroll
    for (int c=0;c<4;c++){
        int n = nt + j4 + c;
        tile[i][j4+c] = (n < Nsz) ? src[(size_t)(kt+i)*Nsz + n] : 0.0f;
    }
    __syncthreads();
    int n = nt + i;
    if (n < Nsz){
#pragma unroll
        for (int c=0;c<4;c++){
            uint16_t hi, lo; split_bf(tile[j4+c][i], hi, lo);
            size_t idx = (size_t)n*Ksz + kt + j4 + c;
            dh[idx] = hi; dl[idx] = lo;
        }
    }
}

__global__ void catb_k(const float* __restrict__ bq, const float* __restrict__ bk,
                       const float* __restrict__ bv, float* __restrict__ dst){
    int j = blockIdx.x*256 + threadIdx.x;
    if (j >= 3072) return;
    int layer = j / 1536, r = j - layer*1536;
    float v;
    if (r < 512)       v = bq[layer*512 + r];
    else if (r < 1024) v = bk[layer*512 + r - 512];
    else               v = bv[layer*512 + r - 1024];
    dst[j] = v;
}

// ---------------------------------------------------------------------------
// MFMA flash attention, split-bf16 QK^T and PV (3-pass each), fp32 softmax.
// Block = (64-row q-tile, h, b). 4 waves, each owns a 16-row Q band.
// ---------------------------------------------------------------------------
__global__ __launch_bounds__(256, 2)
void attnm_k(const uint16_t* __restrict__ qh, const uint16_t* __restrict__ ql,
             const uint16_t* __restrict__ kh, const uint16_t* __restrict__ kl,
             const uint16_t* __restrict__ vth, const uint16_t* __restrict__ vtl,
             uint16_t* __restrict__ oh, uint16_t* __restrict__ ol)
{
    const int qt = blockIdx.x;      // 0..8
    const int h  = blockIdx.y;
    const int b  = blockIdx.z;
    const int bh = b*HH + h;
    const int q0 = qt*64;
    const int tid  = threadIdx.x;
    const int lane = tid & 63;
    const int wu   = __builtin_amdgcn_readfirstlane(tid >> 6);
    const int mrow = lane & 15;     // fragment row index
    const int kgrp = lane >> 4;     // 0..3 k-group

    __shared__ uint16_t Khs[4096], Kls[4096];   // K tile  [64 s][64 d]
    __shared__ uint16_t Vhs[4096], Vls[4096];   // V^T tile [64 d][64 s]
    __shared__ uint16_t Phs[4096], Pls[4096];   // P tile  [64 t][64 s]

    // ---- Q fragments, register resident (hi/lo x 2 ksteps) ----
    int tq = q0 + wu*16 + mrow; if (tq > TT-1) tq = TT-1;
    const uint16_t* qbase = qh + ((size_t)bh*TT + tq)*64 + kgrp*8;
    const uint16_t* qbasl = ql + ((size_t)bh*TT + tq)*64 + kgrp*8;
    bf16x8 qfh[2], qfl[2];
    qfh[0] = ldb8(qbase);      qfh[1] = ldb8(qbase + 32);
    qfl[0] = ldb8(qbasl);      qfl[1] = ldb8(qbasl + 32);

    // staging lane mapping (8 rows of 128B per wave-load, swizzled source)
    const int srw = lane >> 3;      // 0..7
    const int sg  = lane & 7;       // dest granule

    f32x4 oacc[4];
#pragma unroll
    for (int f=0;f<4;f++) oacc[f] = (f32x4){0.f,0.f,0.f,0.f};
    float m_r[4] = {-1e30f,-1e30f,-1e30f,-1e30f};
    float l_r[4] = {0.f,0.f,0.f,0.f};

    for (int st=0; st<9; ++st){
        const int s0 = st*64;
        __syncthreads();   // all waves done reading previous K/V tile
        // ---- stage K and V^T (pre-swizzled source, linear LDS dest) ----
#pragma unroll
        for (int c=0;c<2;c++){
            const int r   = wu*16 + c*8 + srw;       // tile row 0..63
            const int gsl = sg ^ (r & 7);
            int sk = s0 + r; if (sk > TT-1) sk = TT-1;
            const uint16_t* ksh_ = kh  + ((size_t)bh*TT + sk)*64 + gsl*8;
            const uint16_t* ksl_ = kl  + ((size_t)bh*TT + sk)*64 + gsl*8;
            int cb = s0 + gsl*8; if (cb > VSTR-8) cb = VSTR-8;
            const uint16_t* vsh_ = vth + ((size_t)bh*64 + r)*VSTR + cb;
            const uint16_t* vsl_ = vtl + ((size_t)bh*64 + r)*VSTR + cb;
            uint16_t* dst = (uint16_t*)nullptr;
            (void)dst;
            gl16(ksh_, &Khs[(wu*16 + c*8)*64]);
            gl16(ksl_, &Kls[(wu*16 + c*8)*64]);
            gl16(vsh_, &Vhs[(wu*16 + c*8)*64]);
            gl16(vsl_, &Vls[(wu*16 + c*8)*64]);
        }
        __syncthreads();   // staging complete (vmcnt drained by barrier)

        // ---- S = Q K^T (split 3-pass), fp32 accum ----
        f32x4 sacc[4];
#pragma unroll
        for (int f=0;f<4;f++) sacc[f] = (f32x4){0.f,0.f,0.f,0.f};
#pragma unroll
        for (int ks=0; ks<2; ks++){
#pragma unroll
            for (int f=0; f<4; f++){
                const int sr = f*16 + mrow;
                const int sl = ((ks*4 + kgrp) ^ (sr & 7))*8;
                bf16x8 kbh = ldb8(&Khs[sr*64 + sl]);
                bf16x8 kbl = ldb8(&Kls[sr*64 + sl]);
                sacc[f] = __builtin_amdgcn_mfma_f32_16x16x32_bf16(qfh[ks], kbh, sacc[f], 0,0,0);
                sacc[f] = __builtin_amdgcn_mfma_f32_16x16x32_bf16(qfh[ks], kbl, sacc[f], 0,0,0);
                sacc[f] = __builtin_amdgcn_mfma_f32_16x16x32_bf16(qfl[ks], kbh, sacc[f], 0,0,0);
            }
        }

        // ---- online softmax (rows owned: kgrp*4 + r) ----
        float alpha[4];
#pragma unroll
        for (int r=0;r<4;r++){
            float mx = -1e30f;
#pragma unroll
            for (int f=0;f<4;f++){
                float sv = sacc[f][r]*0.125f;
                if (s0 + f*16 + mrow >= TT) sv = -1e30f;
                sacc[f][r] = sv;
                mx = fmaxf(mx, sv);
            }
#pragma unroll
            for (int msk=1; msk<16; msk<<=1) mx = fmaxf(mx, __shfl_xor(mx, msk));
            float mn = fmaxf(m_r[r], mx);
            alpha[r] = __expf(m_r[r] - mn);
            m_r[r] = mn;
            float rs = 0.0f;
#pragma unroll
            for (int f=0;f<4;f++){
                float e = __expf(sacc[f][r] - mn);
                sacc[f][r] = e;
                rs += e;
            }
#pragma unroll
            for (int msk=1; msk<16; msk<<=1) rs += __shfl_xor(rs, msk);
            l_r[r] = l_r[r]*alpha[r] + rs;
#pragma unroll
            for (int f=0;f<4;f++) oacc[f][r] *= alpha[r];
        }

        // ---- write P split-bf16 to LDS (swizzled; wave-private rows) ----
#pragma unroll
        for (int r=0;r<4;r++){
            const int tr = wu*16 + kgrp*4 + r;
#pragma unroll
            for (int f=0;f<4;f++){
                const int c = f*16 + mrow;
                const int idx = tr*64 + ((c>>3) ^ (tr&7))*8 + (c&7);
                uint16_t hi, lo; split_bf(sacc[f][r], hi, lo);
                Phs[idx] = hi; Pls[idx] = lo;
            }
        }
        // same-wave DS ops execute in order; reads below only touch rows this
        // wave wrote, so no barrier is required.

        // ---- O += P V (split 3-pass) ----
#pragma unroll
        for (int ks=0; ks<2; ks++){
            const int trr = wu*16 + mrow;
            const int psl = ((ks*4 + kgrp) ^ (trr & 7))*8;
            bf16x8 pah = ldb8(&Phs[trr*64 + psl]);
            bf16x8 pal = ldb8(&Pls[trr*64 + psl]);
#pragma unroll
            for (int f=0; f<4; f++){
                const int dr = f*16 + mrow;
                const int vsl = ((ks*4 + kgrp) ^ (dr & 7))*8;
                bf16x8 vbh = ldb8(&Vhs[dr*64 + vsl]);
                bf16x8 vbl = ldb8(&Vls[dr*64 + vsl]);
                oacc[f] = __builtin_amdgcn_mfma_f32_16x16x32_bf16(pah, vbh, oacc[f], 0,0,0);
                oacc[f] = __builtin_amdgcn_mfma_f32_16x16x32_bf16(pah, vbl, oacc[f], 0,0,0);
                oacc[f] = __builtin_amdgcn_mfma_f32_16x16x32_bf16(pal, vbh, oacc[f], 0,0,0);
            }
        }
    }

    // ---- epilogue: O/l, split-bf16 store ----
#pragma unroll
    for (int r=0;r<4;r++){
        const int t = q0 + wu*16 + kgrp*4 + r;
        if (t < TT){
            const float inv = 1.0f / l_r[r];
#pragma unroll
            for (int f=0;f<4;f++){
                const int d = f*16 + mrow;
                uint16_t hi, lo; split_bf(oacc[f][r]*inv, hi, lo);
                size_t o = ((size_t)(b*TT + t))*DD + h*DHD + d;
                oh[o] = hi; ol[o] = lo;
            }
        }
    }
}

// ---------------------------------------------------------------------------
// Residual + LayerNorm (unchanged)
// ---------------------------------------------------------------------------
__global__ __launch_bounds__(256)
void ln_k(const float* __restrict__ src, const float* __restrict__ res,
          const float* __restrict__ w, const float* __restrict__ bia,
          float* __restrict__ dst, uint16_t* __restrict__ dbh,
          uint16_t* __restrict__ dbl)
{
    const int r = blockIdx.x;
    const int tid = threadIdx.x;
    const float* sp = src + (size_t)r*DD;
    float x0 = sp[tid], x1 = sp[tid + 256];
    if (res){
        x0 += res[(size_t)r*DD + tid];
        x1 += res[(size_t)r*DD + tid + 256];
    }
    float s  = x0 + x1;
    float sq = x0*x0 + x1*x1;
#pragma unroll
    for (int msk=1; msk<64; msk<<=1){
        s  += __shfl_xor(s,  msk);
        sq += __shfl_xor(sq, msk);
    }
    __shared__ float sm[8];
    int wv = tid >> 6, ln = tid & 63;
    if (ln == 0){ sm[wv] = s; sm[wv+4] = sq; }
    __syncthreads();
    s  = sm[0]+sm[1]+sm[2]+sm[3];
    sq = sm[4]+sm[5]+sm[6]+sm[7];
    float mu  = s * (1.0f/512.0f);
    float var = sq * (1.0f/512.0f) - mu*mu;
    float rsd = rsqrtf(var + 1e-5f);
    float y0 = (x0 - mu)*rsd*w[tid]       + bia[tid];
    float y1 = (x1 - mu)*rsd*w[tid + 256] + bia[tid + 256];
    dst[(size_t)r*DD + tid]       = y0;
    dst[(size_t)r*DD + tid + 256] = y1;
    uint16_t hi, lo;
    split_bf(y0, hi, lo); dbh[(size_t)r*DD + tid] = hi;       dbl[(size_t)r*DD + tid] = lo;
    split_bf(y1, hi, lo); dbh[(size_t)r*DD + tid + 256] = hi; dbl[(size_t)r*DD + tid + 256] = lo;
}

// ---------------------------------------------------------------------------
// sims (unchanged from round 4)
// ---------------------------------------------------------------------------
__global__ __launch_bounds__(256, 2)
void sims_k(const float* __restrict__ pred, const float* __restrict__ bank,
            float* __restrict__ dotp, float* __restrict__ nrmp)
{
    const int jt = blockIdx.x, kt = blockIdx.y;
    const int tid  = threadIdx.x;
    const int lane = tid & 63;
    const int w    = tid >> 6;
    const int qq   = lane & 15;
    const int rep  = lane >> 4;
    const int sb   = (w*4 + rep)*16;
    const int srow = tid >> 4;
    const int tau  = tid & 15;

    __shared__ float BS[16*264];

    const int jr = jt*16 + srow;
    const float* bsrc = (jr < MM) ? (bank + (size_t)jr*PN)
                                  : (pred + (size_t)(jr - MM)*PN);
    bsrc += (size_t)kt*SCHUNK + tau*4;
    const float* psrc = pred + (size_t)qq*PN + (size_t)kt*SCHUNK + sb;

    float acc[16];
#pragma unroll
    for (int j=0;j<16;j++) acc[j] = 0.0f;
    float nr = 0.0f;

    for (int st=0; st<SSTG; ++st){
        float4 blv[4];
#pragma unroll
        for (int c=0;c<4;c++) blv[c] = *(const float4*)(bsrc + c*64);
        float4 pr[4];
#pragma unroll
        for (int i=0;i<4;i++) pr[i] = *(const float4*)(psrc + i*4);
        __syncthreads();
#pragma unroll
        for (int c=0;c<4;c++){
            *(float4*)&BS[srow*264 + tau*4 + c*64] = blv[c];
            nr = fmaf(blv[c].x, blv[c].x, nr);
            nr = fmaf(blv[c].y, blv[c].y, nr);
            nr = fmaf(blv[c].z, blv[c].z, nr);
            nr = fmaf(blv[c].w, blv[c].w, nr);
        }
        __syncthreads();
#pragma unroll
        for (int j=0;j<16;j++){
            float a = acc[j];
#pragma unroll
            for (int i=0;i<4;i++){
                float4 bv = *(const float4*)&BS[j*264 + sb + i*4];
                a = fmaf(bv.x, pr[i].x, a);
                a = fmaf(bv.y, pr[i].y, a);
                a = fmaf(bv.z, pr[i].z, a);
                a = fmaf(bv.w, pr[i].w, a);
            }
            acc[j] = a;
        }
        bsrc += 256; psrc += 256;
    }

    __syncthreads();
    float* RED = BS;
    const int slot = w*4 + rep;
#pragma unroll
    for (int j=0;j<16;j++) RED[(slot*16 + j)*16 + qq] = acc[j];
#pragma unroll
    for (int m=1;m<16;m<<=1) nr += __shfl_xor(nr, m);
    __syncthreads();
    const int j2 = tid >> 4, q2 = tid & 15;
    float s = 0.0f;
#pragma unroll
    for (int s16=0;s16<16;s16++) s += RED[(s16*16 + j2)*16 + q2];
    dotp[((size_t)kt*528 + jt*16 + j2)*16 + q2] = s;
    if (tau == 0) nrmp[kt*528 + jt*16 + srow] = nr;
}

__global__ void norms_k(const float* __restrict__ nrmp, float* __restrict__ invn){
    int j = blockIdx.x*blockDim.x + threadIdx.x;
    if (j < 528){
        float s = 0.0f;
        for (int kt=0; kt<SKC; kt++) s += nrmp[kt*528 + j];
        invn[j] = 1.0f/(sqrtf(s) + 1e-8f);
    }
}

__global__ void simsfin_k(const float* __restrict__ dotp, const float* __restrict__ invn,
                          float* __restrict__ sims){
    int fid = blockIdx.x*256 + threadIdx.x;
    int j = fid >> 4, q = fid & 15;
    float s = 0.0f;
    for (int kt=0; kt<SKC; kt++) s += dotp[((size_t)kt*528 + j)*16 + q];
    sims[q*528 + j] = s * invn[j] * invn[MM + q];
}

__global__ __launch_bounds__(64)
void topk_k(const float* __restrict__ sims, int* __restrict__ idx){
    const int q = blockIdx.x;
    const int lane = threadIdx.x;
    __shared__ float vals[528];
    for (int j=lane; j<528; j+=64) vals[j] = sims[q*528 + j];
    __syncthreads();
    for (int kk=0; kk<KNN; kk++){
        float bv = -3.0e38f; int bi = 1<<30;
        for (int j=lane; j<528; j+=64){
            float v2 = vals[j];
            if (v2 > bv || (v2 == bv && j < bi)){ bv = v2; bi = j; }
        }
#pragma unroll
        for (int msk=1; msk<64; msk<<=1){
            float ov = __shfl_xor(bv, msk);
            int   oi = __shfl_xor(bi, msk);
            if (ov > bv || (ov == bv && oi < bi)){ bv = ov; bi = oi; }
        }
        if (lane == 0){
            idx[q*KNN + kk] = bi;
            vals[bi] = -3.0e38f;
        }
        __syncthreads();
    }
}

__global__ __launch_bounds__(256)
void fuse_k(const float* __restrict__ pred, const float* __restrict__ bank,
            const int* __restrict__ idx, float* __restrict__ out){
    int u = blockIdx.x*256 + threadIdx.x;
    int b = u / (PN/4);
    int e = (u - b*(PN/4)) * 4;
    int id[KNN];
#pragma unroll
    for (int k2=0;k2<KNN;k2++) id[k2] = idx[b*KNN + k2];
    float4 pv = *(const float4*)(pred + (size_t)b*PN + e);
    float ax = 0.5f*pv.x, ay = 0.5f*pv.y, az = 0.5f*pv.z, aw = 0.5f*pv.w;
#pragma unroll
    for (int k2=0;k2<KNN;k2++){
        const float* rp = (id[k2] < MM) ? (bank + (size_t)id[k2]*PN)
                                        : (pred + (size_t)(id[k2]-MM)*PN);
        float4 rv = *(const float4*)(rp + e);
        ax = fmaf(0.05f, rv.x, ax); ay = fmaf(0.05f, rv.y, ay);
        az = fmaf(0.05f, rv.z, az); aw = fmaf(0.05f, rv.w, aw);
    }
    float4 ov; ov.x=ax; ov.y=ay; ov.z=az; ov.w=aw;
    *(float4*)(out + (size_t)b*PN + e) = ov;
}

// ---------------------------------------------------------------------------
extern "C" void kernel_launch(void* const* d_in, const int* in_sizes, int n_in,
                              void* d_out, int out_size, void* d_ws, size_t ws_size,
                              hipStream_t stream)
{
    (void)in_sizes; (void)n_in; (void)out_size; (void)ws_size;
    const float* x_enc  = (const float*)d_in[0];
    const float* x_mark = (const float*)d_in[1];
    const float* W_emb  = (const float*)d_in[4];
    const float* b_emb  = (const float*)d_in[5];
    const float* Wq  = (const float*)d_in[6];
    const float* Wk  = (const float*)d_in[7];
    const float* Wv  = (const float*)d_in[8];
    const float* Wo  = (const float*)d_in[9];
    const float* bq  = (const float*)d_in[10];
    const float* bk  = (const float*)d_in[11];
    const float* bv_ = (const float*)d_in[12];
    const float* bo  = (const float*)d_in[13];
    const float* ln1w = (const float*)d_in[14];
    const float* ln1b = (const float*)d_in[15];
    const float* ln2w = (const float*)d_in[16];
    const float* ln2b = (const float*)d_in[17];
    const float* Wff1 = (const float*)d_in[18];
    const float* bff1 = (const float*)d_in[19];
    const float* Wff2 = (const float*)d_in[20];
    const float* bff2 = (const float*)d_in[21];
    const float* lnfw = (const float*)d_in[22];
    const float* lnfb = (const float*)d_in[23];
    const float* Wproj = (const float*)d_in[24];
    const float* bproj = (const float*)d_in[25];
    const float* bank  = (const float*)d_in[26];
    float* out = (float*)d_out;

    char* pp = (char*)d_ws;
    auto a16 = [&](size_t elems)->uint16_t*{ uint16_t* r=(uint16_t*)pp; pp += ((elems*2 + 255)/256)*256; return r; };
    auto af  = [&](size_t elems)->float*  { float* r=(float*)pp;  pp += ((elems*4 + 255)/256)*256; return r; };

    uint16_t* wembT_h = a16(262144);        uint16_t* wembT_l = a16(262144);
    uint16_t* wqkvT_h = a16(2*1536*512);    uint16_t* wqkvT_l = a16(2*1536*512);
    uint16_t* woT_h   = a16(2*262144);      uint16_t* woT_l   = a16(2*262144);
    uint16_t* wff1T_h = a16(2*2048*512);    uint16_t* wff1T_l = a16(2*2048*512);
    uint16_t* wff2T_h = a16(2*512*2048);    uint16_t* wff2T_l = a16(2*512*2048);
    uint16_t* wprjT_h = a16(172032);        uint16_t* wprjT_l = a16(172032);
    float*    bqkv    = af(3072);
    uint16_t* hb_h    = a16((size_t)BT*512);
    uint16_t* hb_l    = a16((size_t)BT*512);
    uint16_t* tok_h   = a16((size_t)BT*512);     // og fp32 aliases tok region
    uint16_t* tok_l   = a16((size_t)BT*512);
    float*    og      = (float*)tok_h;
    // attention operand region (aliased by midb during FF)
    uint16_t* qsh     = a16((size_t)128*TT*64);
    uint16_t* qsl     = a16((size_t)128*TT*64);
    uint16_t* ksh     = a16((size_t)128*TT*64);
    uint16_t* ksl     = a16((size_t)128*TT*64);
    uint16_t* vsh     = a16((size_t)128*64*VSTR + 4096);
    uint16_t* vsl     = a16((size_t)128*64*VSTR + 4096);
    uint16_t* t1b_h   = a16((size_t)BT*512);
    uint16_t* t1b_l   = a16((size_t)BT*512);
    uint16_t* midb_h  = qsh;                     // mid aliases qsh..t1b region
    uint16_t* midb_l  = midb_h + (size_t)BT*2048;
    float*    h       = af((size_t)BT*512);
    float*    pred    = af((size_t)BB*PN);
    float*    dotp    = af((size_t)SKC*528*16);
    float*    nrmp    = af(SKC*528);
    float*    invn    = af(528);
    float*    sims    = af(16*528);
    int*      idxp    = (int*)af(256);

    dim3 blk(256);

    // ---- input/weight prep ----
    tok_k<<<dim3(17,16,BB), blk, 0, stream>>>(x_enc, x_mark, tok_h, tok_l);
    wtr_k<<<dim3(16,16,1), blk, 0, stream>>>(W_emb, wembT_h, wembT_l, 512, 512, 262144);
    wtr_k<<<dim3(16,16,2), blk, 0, stream>>>(Wq, wqkvT_h,          wqkvT_l,          512, 512, 786432);
    wtr_k<<<dim3(16,16,2), blk, 0, stream>>>(Wk, wqkvT_h + 262144, wqkvT_l + 262144, 512, 512, 786432);
    wtr_k<<<dim3(16,16,2), blk, 0, stream>>>(Wv, wqkvT_h + 524288, wqkvT_l + 524288, 512, 512, 786432);
    wtr_k<<<dim3(16,16,2), blk, 0, stream>>>(Wo, woT_h, woT_l, 512, 512, 262144);
    wtr_k<<<dim3(64,16,2), blk, 0, stream>>>(Wff1, wff1T_h, wff1T_l, 512, 2048, 1048576);
    wtr_k<<<dim3(16,64,2), blk, 0, stream>>>(Wff2, wff2T_h, wff2T_l, 2048, 512, 1048576);
    wtr_k<<<dim3(11,16,1), blk, 0, stream>>>(Wproj, wprjT_h, wprjT_l, 512, 336, 172032);
    catb_k<<<dim3(12), blk, 0, stream>>>(bq, bk, bv_, bqkv);

    // ---- embedding GEMM ----
    bgemm<64, EPI_F32|EPI_BF16><<<dim3(8,65), blk, 0, stream>>>(
        tok_h, tok_l, wembT_h, wembT_l, b_emb, h, hb_h, hb_l,
        nullptr, nullptr, nullptr, nullptr, BT, 512, 512);

    for (int i=0;i<2;i++){
        bgemm<128, EPI_QKV><<<dim3(12,65), blk, 0, stream>>>(
            hb_h, hb_l, wqkvT_h + (size_t)i*786432, wqkvT_l + (size_t)i*786432,
            bqkv + i*1536, nullptr, qsh, qsl, ksh, ksl, vsh, vsl, BT, 1536, 512);
        attnm_k<<<dim3(9,HH,BB), blk, 0, stream>>>(qsh, qsl, ksh, ksl, vsh, vsl, t1b_h, t1b_l);
        bgemm<64, EPI_F32><<<dim3(8,65), blk, 0, stream>>>(
            t1b_h, t1b_l, woT_h + (size_t)i*262144, woT_l + (size_t)i*262144,
            bo + i*512, og, nullptr, nullptr,
            nullptr, nullptr, nullptr, nullptr, BT, 512, 512);
        ln_k<<<BT, blk, 0, stream>>>(h, og, ln1w + i*512, ln1b + i*512, h, hb_h, hb_l);
        bgemm<128, EPI_GELU|EPI_BF16><<<dim3(16,65), blk, 0, stream>>>(
            hb_h, hb_l, wff1T_h + (size_t)i*1048576, wff1T_l + (size_t)i*1048576,
            bff1 + i*DFFN, nullptr, midb_h, midb_l,
            nullptr, nullptr, nullptr, nullptr, BT, DFFN, 512);
        bgemm<64, EPI_F32><<<dim3(8,65), blk, 0, stream>>>(
            midb_h, midb_l, wff2T_h + (size_t)i*1048576, wff2T_l + (size_t)i*1048576,
            bff2 + i*512, og, nullptr, nullptr,
            nullptr, nullptr, nullptr, nullptr, BT, 512, DFFN);
        ln_k<<<BT, blk, 0, stream>>>(h, og, ln2w + i*512, ln2b + i*512, h, hb_h, hb_l);
    }

    ln_k<<<BT, blk, 0, stream>>>(h, nullptr, lnfw, lnfb, h, hb_h, hb_l);

    bgemm<64, EPI_PREDT><<<dim3(6,65), blk, 0, stream>>>(
        hb_h, hb_l, wprjT_h, wprjT_l, bproj, pred, nullptr, nullptr,
        nullptr, nullptr, nullptr, nullptr, BT, PP, 512);

    sims_k<<<dim3(33,SKC), blk, 0, stream>>>(pred, bank, dotp, nrmp);
    norms_k<<<dim3(3), blk, 0, stream>>>(nrmp, invn);
    simsfin_k<<<dim3(33), blk, 0, stream>>>(dotp, invn, sims);
    topk_k<<<dim3(BB), dim3(64), 0, stream>>>(sims, idxp);
    fuse_k<<<dim3((BB*PN/4)/256), blk, 0, stream>>>(pred, bank, idxp, out);
}